// Round 2
// baseline (6724.820 us; speedup 1.0000x reference)
//
#include <hip/hip_runtime.h>
#include <hip/hip_bf16.h>

typedef __hip_bfloat16 bf16;
#define DEV __device__ __forceinline__

// Adaptive input load: flag==1 -> fp32 data, flag==0 -> bf16 data.
DEV float ldin(const void* p, long long i, int f) {
  return f ? ((const float*)p)[i] : __bfloat162float(((const bf16*)p)[i]);
}

// ------------------------------------------------------------ dtype detector
// bf16 N(0,1)/U(0,1) data never has |x|>=128; fp32 data read as bf16 has
// ~47% of low-halves with exponent >= 0x86. Deterministic.
__global__ void k_detect(const void* __restrict__ dist, int* __restrict__ flag) {
  const unsigned short* p = (const unsigned short*)dist;
  __shared__ int bad;
  if (threadIdx.x == 0) bad = 0;
  __syncthreads();
  int cnt = 0;
  for (int i = threadIdx.x; i < 65536; i += 256) {
    unsigned e = (p[i] >> 7) & 0xFF;
    if (e >= 0x86) cnt++;
  }
  atomicAdd(&bad, cnt);
  __syncthreads();
  if (threadIdx.x == 0) *flag = (bad > 100) ? 1 : 0;
}

// ---------------------------------------------------------------- NMS helpers
__global__ void k_cast(const void* __restrict__ s, float* __restrict__ d,
                       const int* __restrict__ flagp) {
  const int f = *flagp;
  int g = blockIdx.x * 256 + threadIdx.x;
  if (g < 20000) d[g] = ldin(s, g, f);
}

__global__ void k_mp5(const float* __restrict__ src, float* __restrict__ dst) {
  int g = blockIdx.x * 256 + threadIdx.x;
  if (g >= 20000) return;
  int bb = g / 5000, rem = g % 5000, y = rem / 100, x = rem % 100;
  const float* p = src + bb * 5000;
  int y0 = y - 2 < 0 ? 0 : y - 2, y1 = y + 2 > 49 ? 49 : y + 2;
  int x0 = x - 2 < 0 ? 0 : x - 2, x1 = x + 2 > 99 ? 99 : x + 2;
  float m = -INFINITY;
  for (int yy = y0; yy <= y1; yy++)
    for (int xx = x0; xx <= x1; xx++)
      m = fmaxf(m, p[yy * 100 + xx]);
  dst[g] = m;
}

__global__ void k_eq(const float* __restrict__ a, const float* __restrict__ b,
                     float* __restrict__ mk) {
  int g = blockIdx.x * 256 + threadIdx.x;
  if (g < 20000) mk[g] = (a[g] == b[g]) ? 1.f : 0.f;
}

__global__ void k_supp(const float* __restrict__ mpmk, const float* __restrict__ s0,
                       float* __restrict__ sup, float* __restrict__ ss) {
  int g = blockIdx.x * 256 + threadIdx.x;
  if (g >= 20000) return;
  bool s = mpmk[g] > 0.f;
  sup[g] = s ? 1.f : 0.f;
  ss[g] = s ? 0.f : s0[g];
}

__global__ void k_upd(float* __restrict__ mk, const float* __restrict__ ss,
                      const float* __restrict__ mpss, const float* __restrict__ sup) {
  int g = blockIdx.x * 256 + threadIdx.x;
  if (g >= 20000) return;
  if (mk[g] == 0.f) mk[g] = ((ss[g] == mpss[g]) && (sup[g] == 0.f)) ? 1.f : 0.f;
}

// ------------------------------------------------ exact top-k via bitonic sort
__global__ __launch_bounds__(1024) void k_sort(
    const float* __restrict__ s0, const float* __restrict__ mk,
    int* __restrict__ idxO, float* __restrict__ valsO, float* __restrict__ maskO) {
  __shared__ unsigned long long keys[8192];
  const int bb = blockIdx.x;
  const int t = threadIdx.x;
  for (int i = t; i < 8192; i += 1024) {
    unsigned long long kk;
    if (i < 5000) {
      float v = (mk[bb * 5000 + i] != 0.f) ? s0[bb * 5000 + i] : 0.f;
      unsigned vb = __float_as_uint(v);  // scores >= 0 -> monotone bits
      kk = ((unsigned long long)vb << 32) | (unsigned)(0xFFFFFFFFu - (unsigned)i);
    } else {
      kk = 0ull;  // pad sorts last
    }
    keys[i] = ~kk;
  }
  __syncthreads();
  for (int k = 2; k <= 8192; k <<= 1) {
    for (int j = k >> 1; j > 0; j >>= 1) {
      for (int i = t; i < 8192; i += 1024) {
        int ixj = i ^ j;
        if (ixj > i) {
          unsigned long long a = keys[i], b = keys[ixj];
          bool up = ((i & k) == 0);
          if (up ? (a > b) : (a < b)) { keys[i] = b; keys[ixj] = a; }
        }
      }
      __syncthreads();
    }
  }
  {
    unsigned long long kk = ~keys[t];
    unsigned idx = 0xFFFFFFFFu - (unsigned)(kk & 0xFFFFFFFFu);
    float v = __uint_as_float((unsigned)(kk >> 32));
    idxO[bb * 1024 + t] = (int)idx;
    valsO[bb * 1024 + t] = v;
    maskO[bb * 1024 + t] = (v > 0.015f) ? 1.f : 0.f;
  }
}

// --------------------------------------------------------- embedding build
__global__ void k_emb(const int* __restrict__ idxO, const float* __restrict__ valsO,
                      const void* __restrict__ distance, float* __restrict__ emb,
                      const int* __restrict__ flagp) {
  const int f = *flagp;
  const int vtx = blockIdx.x;          // 0..4095
  const int bb = vtx >> 10, i = vtx & 1023;
  const int t = threadIdx.x;
  const int id = idxO[bb * 1024 + i];
  const int cy = id / 100, cx = id % 100;
  const float nvx = ((float)cx - 50.0f + 0.5f) / 100.0f;
  const float nvy = ((float)cy - 25.0f + 0.5f) / 50.0f;
  float* e = emb + (long long)vtx * 235;
  for (int c = t; c < 235; c += 256) {
    float val;
    if (c == 0) val = nvx;
    else if (c == 1) val = nvy;
    else if (c < 42) {
      int d = c - 2, fq = d >> 2, r = d & 3;
      float freq = (float)(1 << fq);
      float ang = ((r == 0 || r == 2) ? nvx : nvy) * freq;
      val = (r < 2) ? sinf(ang) : cosf(ang);
    } else if (c == 42) {
      val = valsO[bb * 1024 + i];
    } else {
      int d = c - 43, cls = d >> 6, ii = (d >> 3) & 7, jj = d & 7;
      val = ldin(distance,
                 (((long long)bb * 3 + cls) * 400 + (cy * 8 + ii)) * 800 + (cx * 8 + jj), f);
    }
    e[c] = val;
  }
}

// ----------------------------------------------------------------- GEMM (NT)
// out[m,n] = sum_k A[m,k]*W[n,k] (+epilogue). MODE: 0 +bias; 1 +bias,BN,ReLU;
// 2 +bias+resid; 3 +bias, permuted store [b,h,n,d]; 4 *scale (Gram).
// WIN: W/bias/bn are model inputs (dtype via flag); else fp32 workspace.
template <int MODE, bool WIN>
__global__ __launch_bounds__(256) void gemm_nt(
    const float* __restrict__ A, int lda, const void* __restrict__ W,
    const void* __restrict__ bias, const void* __restrict__ bn,
    const float* __restrict__ resid, float* __restrict__ Cout, int ldc,
    int M, int N, int K, float scale,
    long long aBatch, long long wBatch, long long cBatch,
    long long wOff, long long bOff, long long bnOff, const int* __restrict__ flagp) {
  const int wf = WIN ? *flagp : 1;
  A += (long long)blockIdx.z * aBatch;
  const long long wbase = wOff + (long long)blockIdx.z * wBatch;
  Cout += (long long)blockIdx.z * cBatch;
  __shared__ float As[32][68];
  __shared__ float Bs[32][68];
  const int t = threadIdx.x;
  const int m0 = blockIdx.y * 64, n0 = blockIdx.x * 64;
  const int tx = t & 15, ty = t >> 4;
  float acc[4][4] = {};
  for (int k0 = 0; k0 < K; k0 += 32) {
#pragma unroll
    for (int i = 0; i < 8; i++) {
      int id = t + i * 256;
      int r = id >> 5, c = id & 31;
      int kc = k0 + c;
      As[c][r] = (kc < K) ? A[(long long)(m0 + r) * lda + kc] : 0.f;
      Bs[c][r] = (kc < K) ? ldin(W, wbase + (long long)(n0 + r) * K + kc, wf) : 0.f;
    }
    __syncthreads();
#pragma unroll
    for (int kk = 0; kk < 32; kk++) {
      const float4 a4 = *(const float4*)(&As[kk][ty << 2]);
      const float4 b4 = *(const float4*)(&Bs[kk][tx << 2]);
      const float av[4] = {a4.x, a4.y, a4.z, a4.w};
      const float bv[4] = {b4.x, b4.y, b4.z, b4.w};
#pragma unroll
      for (int ii = 0; ii < 4; ii++)
#pragma unroll
        for (int jj = 0; jj < 4; jj++)
          acc[ii][jj] = fmaf(av[ii], bv[jj], acc[ii][jj]);
    }
    __syncthreads();
  }
#pragma unroll
  for (int ii = 0; ii < 4; ii++) {
    const int m = m0 + (ty << 2) + ii;
#pragma unroll
    for (int jj = 0; jj < 4; jj++) {
      const int n = n0 + (tx << 2) + jj;
      float v = acc[ii][jj];
      if (MODE == 4) {
        v *= scale;
      } else {
        v += ldin(bias, bOff + n, wf);
      }
      if (MODE == 1) {
        const float g = ldin(bn, bnOff + n, wf);
        const float bt = ldin(bn, bnOff + N + n, wf);
        const float mu = ldin(bn, bnOff + 2 * N + n, wf);
        const float vr = ldin(bn, bnOff + 3 * N + n, wf);
        v = g * (v - mu) / sqrtf(vr + 1e-5f) + bt;
        v = fmaxf(v, 0.f);
      }
      if (MODE == 2) v += resid[(long long)m * 256 + n];
      if (MODE == 3) {
        const int bb = m >> 10, nn = m & 1023, h = n & 3, d = n >> 2;
        Cout[(((long long)bb * 4 + h) * 1024 + nn) * 64 + d] = v;
      } else {
        Cout[(long long)m * ldc + n] = v;
      }
    }
  }
}

// -------------------------------------------------- flash-style attention
// Q/K/V layout [b][h][n][64]; out msg row-major [4096][256] with c = d*4+h.
__global__ __launch_bounds__(256) void k_attn(
    const float* __restrict__ Q, const float* __restrict__ K,
    const float* __restrict__ V, const float* __restrict__ maskf,
    float* __restrict__ Out) {
  const int qt = blockIdx.x, h = blockIdx.y, bb = blockIdx.z;
  const int t = threadIdx.x;
  const int nl = t >> 3;  // query in tile (0..31)
  const int j8 = t & 7;   // key/dim slice
  __shared__ float Qs[32][65];
  __shared__ float Ks[64][65];
  __shared__ float Vs[64][65];
  __shared__ float Ps[32][65];
  __shared__ float red[32][8];
  __shared__ float mi[32], li[32], alph[32], mnew[32];
  __shared__ float qm[32], km[64];
  const long long hb = ((long long)bb * 4 + h) * 1024;
  const int q0 = qt * 32;
  for (int i = t; i < 32 * 64; i += 256) {
    int n = i >> 6, d = i & 63;
    Qs[n][d] = Q[(hb + q0 + n) * 64 + d];
  }
  if (t < 32) {
    qm[t] = maskf[bb * 1024 + q0 + t];
    mi[t] = -INFINITY;
    li[t] = 0.f;
  }
  float o[8] = {0.f, 0.f, 0.f, 0.f, 0.f, 0.f, 0.f, 0.f};
  __syncthreads();
  for (int kt = 0; kt < 16; kt++) {
    const int k0 = kt * 64;
    for (int i = t; i < 64 * 64; i += 256) {
      int m = i >> 6, d = i & 63;
      Ks[m][d] = K[(hb + k0 + m) * 64 + d];
      Vs[m][d] = V[(hb + k0 + m) * 64 + d];
    }
    if (t < 64) km[t] = maskf[bb * 1024 + k0 + t];
    __syncthreads();
    float sv[8];
#pragma unroll
    for (int mm = 0; mm < 8; mm++) sv[mm] = 0.f;
    for (int d = 0; d < 64; d++) {
      const float qv = Qs[nl][d];
#pragma unroll
      for (int mm = 0; mm < 8; mm++)
        sv[mm] = fmaf(qv, Ks[j8 * 8 + mm][d], sv[mm]);
    }
    float pmax = -INFINITY;
#pragma unroll
    for (int mm = 0; mm < 8; mm++) {
      float s = sv[mm] * 0.125f;
      if (qm[nl] * km[j8 * 8 + mm] == 0.f) s = -1e9f;
      sv[mm] = s;
      pmax = fmaxf(pmax, s);
    }
    red[nl][j8] = pmax;
    __syncthreads();
    if (j8 == 0) {
      float tm = red[nl][0];
#pragma unroll
      for (int i = 1; i < 8; i++) tm = fmaxf(tm, red[nl][i]);
      float nm = fmaxf(mi[nl], tm);
      alph[nl] = expf(mi[nl] - nm);  // expf(-inf)=0 on first tile
      mnew[nl] = nm;
    }
    __syncthreads();
    const float nm = mnew[nl], al = alph[nl];
    float psum = 0.f;
#pragma unroll
    for (int mm = 0; mm < 8; mm++) {
      float p = expf(sv[mm] - nm);
      Ps[nl][j8 * 8 + mm] = p;
      psum += p;
    }
    red[nl][j8] = psum;
#pragma unroll
    for (int dd = 0; dd < 8; dd++) o[dd] *= al;
    __syncthreads();
    for (int m = 0; m < 64; m++) {
      const float p = Ps[nl][m];
#pragma unroll
      for (int dd = 0; dd < 8; dd++)
        o[dd] = fmaf(p, Vs[m][j8 * 8 + dd], o[dd]);
    }
    if (j8 == 0) {
      float s = red[nl][0];
#pragma unroll
      for (int i = 1; i < 8; i++) s += red[nl][i];
      li[nl] = li[nl] * al + s;
      mi[nl] = mnew[nl];
    }
    __syncthreads();
  }
  const float inv = 1.f / li[nl];
  const long long orow = ((long long)bb * 1024 + q0 + nl) * 256;
#pragma unroll
  for (int dd = 0; dd < 8; dd++)
    Out[orow + (long long)(j8 * 8 + dd) * 4 + h] = o[dd] * inv;
}

// ------------------------------------------------------------- misc small
__global__ void k_copy(const float* __restrict__ X, float* __restrict__ XM) {
  int g = blockIdx.x * 256 + threadIdx.x;  // over 262144 float4
  if (g >= 262144) return;
  int r = g >> 6, c = g & 63;
  ((float4*)XM)[(long long)r * 128 + c] = ((const float4*)X)[g];
}

__global__ void k_border(float* __restrict__ C, const void* __restrict__ alpha,
                         const int* __restrict__ flagp) {
  const int f = *flagp;
  int g = blockIdx.x * 256 + threadIdx.x;
  if (g >= 4 * 2050) return;
  float a = ldin(alpha, 0, f);
  int bb = g / 2050, r = g % 2050;
  float* Cb = C + (long long)bb * 1050625;
  if (r < 1025) Cb[(long long)1024 * 1025 + r] = a;
  else Cb[(long long)(r - 1025) * 1025 + 1024] = a;
}

// -------------------------------------------------------------- Sinkhorn
// 4 independent barrier groups (one per batch, 64 blocks each). Cross-block
// traffic via agent-scope atomics (cache-bypassing) so C rows stay L2-warm.
DEV void gbar(unsigned* c, unsigned nblk) {
  __syncthreads();
  if (threadIdx.x == 0) {
    __hip_atomic_fetch_add(c, 1u, __ATOMIC_RELEASE, __HIP_MEMORY_SCOPE_AGENT);
    while (__hip_atomic_load(c, __ATOMIC_ACQUIRE, __HIP_MEMORY_SCOPE_AGENT) < nblk)
      __builtin_amdgcn_s_sleep(2);
  }
  __syncthreads();
}

__global__ __launch_bounds__(512) void k_sinkhorn(
    const float* __restrict__ C, float* u, float* v, unsigned* ctr,
    void* __restrict__ outv, const int* __restrict__ flagp) {
  const int f = *flagp;
  const int bb = blockIdx.x >> 6;
  const int blk = blockIdx.x & 63;
  const int t = threadIdx.x;
  const int wv = (blk << 3) | (t >> 6);  // 0..511 within group
  const int lane = t & 63;
  const float* Cb = C + (long long)bb * 1050625;
  float* ub = u + bb * 1025;
  float* vb = v + bb * 1025;
  unsigned* cg = ctr + bb * 256;
  __shared__ float sv[1025];
  __shared__ float su[1025];
  const float NORM = -7.624619086159398f;  // -log(2048)
  const float BIN = -0.6931471805599453f;  // log(1024)-log(2048)
  for (int half = 0; half < 200; half++) {
    float* src = (half & 1) ? ub : vb;
    float* dst = (half & 1) ? vb : ub;
    for (int i = t; i < 1025; i += 512)
      sv[i] = __hip_atomic_load(src + i, __ATOMIC_RELAXED, __HIP_MEMORY_SCOPE_AGENT);
    __syncthreads();
    for (int n = wv; n < 1025; n += 512) {
      const float* row = Cb + (long long)n * 1025;
      float vals[17];
      float mx = -INFINITY;
#pragma unroll
      for (int i = 0; i < 17; i++) {
        int col = (i << 6) + lane;
        float x = (col <= 1024) ? row[col] + sv[col] : -INFINITY;
        vals[i] = x;
        mx = fmaxf(mx, x);
      }
#pragma unroll
      for (int off = 32; off; off >>= 1) mx = fmaxf(mx, __shfl_xor(mx, off, 64));
      float s = 0.f;
#pragma unroll
      for (int i = 0; i < 17; i++) s += expf(vals[i] - mx);
#pragma unroll
      for (int off = 32; off; off >>= 1) s += __shfl_xor(s, off, 64);
      if (lane == 0) {
        float lmu = (n < 1024) ? NORM : BIN;
        __hip_atomic_store(dst + n, lmu - (mx + logf(s)), __ATOMIC_RELAXED,
                           __HIP_MEMORY_SCOPE_AGENT);
      }
    }
    gbar(cg + half, 64u);
  }
  for (int i = t; i < 1025; i += 512) {
    su[i] = __hip_atomic_load(ub + i, __ATOMIC_RELAXED, __HIP_MEMORY_SCOPE_AGENT);
    sv[i] = __hip_atomic_load(vb + i, __ATOMIC_RELAXED, __HIP_MEMORY_SCOPE_AGENT);
  }
  __syncthreads();
  const long long base = (long long)bb * 1050625;
  for (int i = blk * 512 + t; i < 1050625; i += 64 * 512) {
    int n = i / 1025, m = i - n * 1025;
    float val = Cb[i] + su[n] + sv[m] - NORM;
    if (f) ((float*)outv)[base + i] = val;
    else ((bf16*)outv)[base + i] = __float2bfloat16(val);
  }
}

// ================================================================== launch
extern "C" void kernel_launch(void* const* d_in, const int* in_sizes, int n_in,
                              void* d_out, int out_size, void* d_ws, size_t ws_size,
                              hipStream_t stream) {
  const void* scores = d_in[0];
  const void* distance = d_in[1];
  const void* enc_W0 = d_in[2];
  const void* enc_b0 = d_in[3];
  const void* enc_bn = d_in[4];
  const void* enc_W1 = d_in[5];
  const void* enc_b1 = d_in[6];
  const void* gnn_Wqkv = d_in[7];
  const void* gnn_bqkv = d_in[8];
  const void* gnn_Wm = d_in[9];
  const void* gnn_bm = d_in[10];
  const void* gnn_W1 = d_in[11];
  const void* gnn_b1 = d_in[12];
  const void* gnn_bn = d_in[13];
  const void* gnn_W2 = d_in[14];
  const void* gnn_b2 = d_in[15];
  const void* final_W = d_in[16];
  const void* final_b = d_in[17];
  const void* alpha = d_in[18];
  (void)in_sizes; (void)n_in; (void)out_size; (void)ws_size;

  char* ws = (char*)d_ws;
  size_t off = 0;
  auto alloc = [&](size_t bytes) -> void* {
    void* p = ws + off;
    off += (bytes + 255) & ~(size_t)255;
    return p;
  };
  int* flag = (int*)alloc(256);
  float* s0 = (float*)alloc(20000 * 4);
  float* t0 = (float*)alloc(20000 * 4);
  float* t1 = (float*)alloc(20000 * 4);
  float* mk = (float*)alloc(20000 * 4);
  float* sup = (float*)alloc(20000 * 4);
  int* idxO = (int*)alloc(4096 * 4);
  float* valsO = (float*)alloc(4096 * 4);
  float* maskO = (float*)alloc(4096 * 4);
  float* emb = (float*)alloc((size_t)4096 * 235 * 4);
  float* T0 = (float*)alloc((size_t)4096 * 256 * 4);
  float* X = (float*)alloc((size_t)4096 * 256 * 4);
  float* Qh = (float*)alloc((size_t)4096 * 256 * 4);
  float* Kh = (float*)alloc((size_t)4096 * 256 * 4);
  float* Vh = (float*)alloc((size_t)4096 * 256 * 4);
  float* msgb = (float*)alloc((size_t)4096 * 256 * 4);
  float* XM = (float*)alloc((size_t)4096 * 512 * 4);
  float* Y1 = (float*)alloc((size_t)4096 * 512 * 4);
  float* MD = (float*)alloc((size_t)4096 * 256 * 4);
  float* Cpl = (float*)alloc((size_t)4 * 1050625 * 4);
  float* u = (float*)alloc(4100 * 4);
  float* v = (float*)alloc(4100 * 4);
  unsigned* ctr = (unsigned*)alloc(4 * 256 * 4);

  hipMemsetAsync(u, 0, 4100 * 4, stream);
  hipMemsetAsync(v, 0, 4100 * 4, stream);
  hipMemsetAsync(ctr, 0, 4 * 256 * 4, stream);

  const dim3 b256(256);
  const int g79 = 79;
  k_detect<<<1, b256, 0, stream>>>(distance, flag);
  k_cast<<<g79, b256, 0, stream>>>(scores, s0, flag);
  k_mp5<<<g79, b256, 0, stream>>>(s0, t0);
  k_eq<<<g79, b256, 0, stream>>>(s0, t0, mk);
  for (int r = 0; r < 2; r++) {
    k_mp5<<<g79, b256, 0, stream>>>(mk, t0);
    k_supp<<<g79, b256, 0, stream>>>(t0, s0, sup, t1);
    k_mp5<<<g79, b256, 0, stream>>>(t1, t0);
    k_upd<<<g79, b256, 0, stream>>>(mk, t1, t0, sup);
  }
  k_sort<<<4, 1024, 0, stream>>>(s0, mk, idxO, valsO, maskO);
  k_emb<<<4096, b256, 0, stream>>>(idxO, valsO, distance, emb, flag);

  // encoder: relu(bn(emb@W0^T+b0)) then @W1^T+b1
  gemm_nt<1, true><<<dim3(4, 64, 1), b256, 0, stream>>>(
      emb, 235, enc_W0, enc_b0, enc_bn, nullptr, T0, 256, 4096, 256, 235, 1.f,
      0, 0, 0, 0, 0, 0, flag);
  gemm_nt<0, true><<<dim3(4, 64, 1), b256, 0, stream>>>(
      T0, 256, enc_W1, enc_b1, nullptr, nullptr, X, 256, 4096, 256, 256, 1.f,
      0, 0, 0, 0, 0, 0, flag);

  for (int l = 0; l < 4; l++) {
    for (int qkv = 0; qkv < 3; qkv++) {
      float* dstq = (qkv == 0) ? Qh : (qkv == 1) ? Kh : Vh;
      gemm_nt<3, true><<<dim3(4, 64, 1), b256, 0, stream>>>(
          X, 256, gnn_Wqkv, gnn_bqkv, nullptr, nullptr, dstq, 0, 4096, 256, 256,
          1.f, 0, 0, 0, (long long)(l * 3 + qkv) * 65536,
          (long long)(l * 3 + qkv) * 256, 0, flag);
    }
    k_attn<<<dim3(32, 4, 4), b256, 0, stream>>>(Qh, Kh, Vh, maskO, msgb);
    gemm_nt<0, true><<<dim3(4, 64, 1), b256, 0, stream>>>(
        msgb, 256, gnn_Wm, gnn_bm, nullptr, nullptr, XM + 256, 512, 4096, 256,
        256, 1.f, 0, 0, 0, (long long)l * 65536, (long long)l * 256, 0, flag);
    k_copy<<<1024, b256, 0, stream>>>(X, XM);
    gemm_nt<1, true><<<dim3(8, 64, 1), b256, 0, stream>>>(
        XM, 512, gnn_W1, gnn_b1, gnn_bn, nullptr, Y1, 512, 4096, 512, 512, 1.f,
        0, 0, 0, (long long)l * 262144, (long long)l * 512, (long long)l * 2048, flag);
    gemm_nt<2, true><<<dim3(4, 64, 1), b256, 0, stream>>>(
        Y1, 512, gnn_W2, gnn_b2, nullptr, X, X, 256, 4096, 256, 512, 1.f,
        0, 0, 0, (long long)l * 131072, (long long)l * 256, 0, flag);
  }
  gemm_nt<0, true><<<dim3(4, 64, 1), b256, 0, stream>>>(
      X, 256, final_W, final_b, nullptr, nullptr, MD, 256, 4096, 256, 256, 1.f,
      0, 0, 0, 0, 0, 0, flag);
  // Gram: sc = (MD_b @ MD_b^T)/16 into inner 1024x1024 of couplings (ldc=1025)
  gemm_nt<4, false><<<dim3(16, 16, 4), b256, 0, stream>>>(
      MD, 256, MD, nullptr, nullptr, nullptr, Cpl, 1025, 1024, 1024, 256, 0.0625f,
      262144, 262144, 1050625, 0, 0, 0, flag);
  k_border<<<33, b256, 0, stream>>>(Cpl, alpha, flag);
  k_sinkhorn<<<256, 512, 0, stream>>>(Cpl, u, v, ctr, d_out, flag);
}

// Round 3
// 5996.198 us; speedup vs baseline: 1.1215x; 1.1215x over previous
//
#include <hip/hip_runtime.h>
#include <hip/hip_bf16.h>

typedef __hip_bfloat16 bf16;
#define DEV __device__ __forceinline__

// Adaptive input load: flag==1 -> fp32 data, flag==0 -> bf16 data.
DEV float ldin(const void* p, long long i, int f) {
  return f ? ((const float*)p)[i] : __bfloat162float(((const bf16*)p)[i]);
}

// ------------------------------------------------------------ dtype detector
__global__ void k_detect(const void* __restrict__ dist, int* __restrict__ flag) {
  const unsigned short* p = (const unsigned short*)dist;
  __shared__ int bad;
  if (threadIdx.x == 0) bad = 0;
  __syncthreads();
  int cnt = 0;
  for (int i = threadIdx.x; i < 65536; i += 256) {
    unsigned e = (p[i] >> 7) & 0xFF;
    if (e >= 0x86) cnt++;
  }
  atomicAdd(&bad, cnt);
  __syncthreads();
  if (threadIdx.x == 0) *flag = (bad > 100) ? 1 : 0;
}

// ------------------------------------------------------ fused NMS (one block/batch)
DEV void mp5_sep(const float* in, float* tmp, float* out, int t) {
  for (int i = t; i < 5000; i += 512) {
    int y = i / 100, x = i % 100;
    int x0 = x - 2 < 0 ? 0 : x - 2, x1 = x + 2 > 99 ? 99 : x + 2;
    float m = -INFINITY;
    for (int xx = x0; xx <= x1; xx++) m = fmaxf(m, in[y * 100 + xx]);
    tmp[i] = m;
  }
  __syncthreads();
  for (int i = t; i < 5000; i += 512) {
    int y = i / 100, x = i % 100;
    int y0 = y - 2 < 0 ? 0 : y - 2, y1 = y + 2 > 49 ? 49 : y + 2;
    float m = -INFINITY;
    for (int yy = y0; yy <= y1; yy++) m = fmaxf(m, tmp[yy * 100 + x]);
    out[i] = m;
  }
  __syncthreads();
}

__global__ __launch_bounds__(512) void k_nms(const void* __restrict__ scores,
                                             const int* __restrict__ flagp,
                                             float* __restrict__ sn) {
  const int f = *flagp;
  const int bb = blockIdx.x, t = threadIdx.x;
  __shared__ float S[5000], T[5000], P[5000], MK[5000], SP[5000], SS[5000];
  for (int i = t; i < 5000; i += 512) S[i] = ldin(scores, bb * 5000 + i, f);
  __syncthreads();
  mp5_sep(S, T, P, t);
  for (int i = t; i < 5000; i += 512) MK[i] = (S[i] == P[i]) ? 1.f : 0.f;
  __syncthreads();
  for (int r = 0; r < 2; r++) {
    mp5_sep(MK, T, P, t);
    for (int i = t; i < 5000; i += 512) {
      SP[i] = (P[i] > 0.f) ? 1.f : 0.f;
      SS[i] = (SP[i] != 0.f) ? 0.f : S[i];
    }
    __syncthreads();
    mp5_sep(SS, T, P, t);
    for (int i = t; i < 5000; i += 512)
      if (MK[i] == 0.f) MK[i] = ((SS[i] == P[i]) && (SP[i] == 0.f)) ? 1.f : 0.f;
    __syncthreads();
  }
  for (int i = t; i < 5000; i += 512)
    sn[bb * 5000 + i] = (MK[i] != 0.f) ? S[i] : 0.f;
}

// ------------------------------------------------ exact top-k via bitonic sort
__global__ __launch_bounds__(1024) void k_sort(
    const float* __restrict__ sn,
    int* __restrict__ idxO, float* __restrict__ valsO, float* __restrict__ maskO) {
  __shared__ unsigned long long keys[8192];
  const int bb = blockIdx.x;
  const int t = threadIdx.x;
  for (int i = t; i < 8192; i += 1024) {
    unsigned long long kk;
    if (i < 5000) {
      float v = sn[bb * 5000 + i];
      unsigned vb = __float_as_uint(v);  // scores >= 0 -> monotone bits
      kk = ((unsigned long long)vb << 32) | (unsigned)(0xFFFFFFFFu - (unsigned)i);
    } else {
      kk = 0ull;  // pad sorts last
    }
    keys[i] = ~kk;
  }
  __syncthreads();
  for (int k = 2; k <= 8192; k <<= 1) {
    for (int j = k >> 1; j > 0; j >>= 1) {
      for (int i = t; i < 8192; i += 1024) {
        int ixj = i ^ j;
        if (ixj > i) {
          unsigned long long a = keys[i], b = keys[ixj];
          bool up = ((i & k) == 0);
          if (up ? (a > b) : (a < b)) { keys[i] = b; keys[ixj] = a; }
        }
      }
      __syncthreads();
    }
  }
  {
    unsigned long long kk = ~keys[t];
    unsigned idx = 0xFFFFFFFFu - (unsigned)(kk & 0xFFFFFFFFu);
    float v = __uint_as_float((unsigned)(kk >> 32));
    idxO[bb * 1024 + t] = (int)idx;
    valsO[bb * 1024 + t] = v;
    maskO[bb * 1024 + t] = (v > 0.015f) ? 1.f : 0.f;
  }
}

// --------------------------------------------------------- embedding build
__global__ void k_emb(const int* __restrict__ idxO, const float* __restrict__ valsO,
                      const void* __restrict__ distance, float* __restrict__ emb,
                      const int* __restrict__ flagp) {
  const int f = *flagp;
  const int vtx = blockIdx.x;          // 0..4095
  const int bb = vtx >> 10, i = vtx & 1023;
  const int t = threadIdx.x;
  const int id = idxO[bb * 1024 + i];
  const int cy = id / 100, cx = id % 100;
  const float nvx = ((float)cx - 50.0f + 0.5f) / 100.0f;
  const float nvy = ((float)cy - 25.0f + 0.5f) / 50.0f;
  float* e = emb + (long long)vtx * 235;
  for (int c = t; c < 235; c += 256) {
    float val;
    if (c == 0) val = nvx;
    else if (c == 1) val = nvy;
    else if (c < 42) {
      int d = c - 2, fq = d >> 2, r = d & 3;
      float freq = (float)(1 << fq);
      float ang = ((r == 0 || r == 2) ? nvx : nvy) * freq;
      val = (r < 2) ? sinf(ang) : cosf(ang);
    } else if (c == 42) {
      val = valsO[bb * 1024 + i];
    } else {
      int d = c - 43, cls = d >> 6, ii = (d >> 3) & 7, jj = d & 7;
      val = ldin(distance,
                 (((long long)bb * 3 + cls) * 400 + (cy * 8 + ii)) * 800 + (cx * 8 + jj), f);
    }
    e[c] = val;
  }
}

// ----------------------------------------------------------------- GEMM (NT)
// 32x64 tile (2 blocks/CU for latency hiding). out[m,n]=sum_k A[m,k]*W[n,k].
// MODE: 0 +bias; 1 +bias,BN,ReLU; 2 +bias+resid(in-place X); 3 +bias,
// permuted store [b,h,n,d]; 4 *scale (Gram). WIN: W/bias/bn dtype via flag.
// SPLIT: A k<256 from A, k>=256 from A2 (both lda=256).
template <int MODE, bool WIN, bool SPLIT>
__global__ __launch_bounds__(256) void gemm_nt(
    const float* __restrict__ A, const float* __restrict__ A2, int lda,
    const void* __restrict__ W,
    const void* __restrict__ bias, const void* __restrict__ bn,
    const float* __restrict__ resid, float* __restrict__ Cout, int ldc,
    int M, int N, int K, float scale,
    long long aBatch, long long wBatch, long long cBatch,
    long long wOff, long long bOff, long long bnOff, const int* __restrict__ flagp) {
  const int wf = WIN ? *flagp : 1;
  A += (long long)blockIdx.z * aBatch;
  const long long wbase = wOff + (long long)blockIdx.z * wBatch;
  Cout += (long long)blockIdx.z * cBatch;
  __shared__ float As[32][33];
  __shared__ float Bs[32][68];
  const int t = threadIdx.x;
  const int m0 = blockIdx.y * 32, n0 = blockIdx.x * 64;
  const int tx = t & 15, ty = t >> 4;
  float acc[2][4] = {};
  for (int k0 = 0; k0 < K; k0 += 32) {
#pragma unroll
    for (int i = 0; i < 4; i++) {   // A tile: 32x32
      int id = t + i * 256;
      int r = id >> 5, c = id & 31;
      int kc = k0 + c;
      float av = 0.f;
      if (kc < K) {
        if (SPLIT) av = (kc < 256) ? A[(long long)(m0 + r) * 256 + kc]
                                   : A2[(long long)(m0 + r) * 256 + (kc - 256)];
        else av = A[(long long)(m0 + r) * lda + kc];
      }
      As[c][r] = av;
    }
#pragma unroll
    for (int i = 0; i < 8; i++) {   // B tile: 64x32
      int id = t + i * 256;
      int r = id >> 5, c = id & 31;
      int kc = k0 + c;
      Bs[c][r] = (kc < K) ? ldin(W, wbase + (long long)(n0 + r) * K + kc, wf) : 0.f;
    }
    __syncthreads();
#pragma unroll
    for (int kk = 0; kk < 32; kk++) {
      const float2 a2 = *(const float2*)(&As[kk][ty << 1]);
      const float4 b4 = *(const float4*)(&Bs[kk][tx << 2]);
      const float av[2] = {a2.x, a2.y};
      const float bv[4] = {b4.x, b4.y, b4.z, b4.w};
#pragma unroll
      for (int ii = 0; ii < 2; ii++)
#pragma unroll
        for (int jj = 0; jj < 4; jj++)
          acc[ii][jj] = fmaf(av[ii], bv[jj], acc[ii][jj]);
    }
    __syncthreads();
  }
#pragma unroll
  for (int ii = 0; ii < 2; ii++) {
    const int m = m0 + (ty << 1) + ii;
#pragma unroll
    for (int jj = 0; jj < 4; jj++) {
      const int n = n0 + (tx << 2) + jj;
      float v = acc[ii][jj];
      if (MODE == 4) {
        v *= scale;
      } else {
        v += ldin(bias, bOff + n, wf);
      }
      if (MODE == 1) {
        const float g = ldin(bn, bnOff + n, wf);
        const float bt = ldin(bn, bnOff + N + n, wf);
        const float mu = ldin(bn, bnOff + 2 * N + n, wf);
        const float vr = ldin(bn, bnOff + 3 * N + n, wf);
        v = g * (v - mu) / sqrtf(vr + 1e-5f) + bt;
        v = fmaxf(v, 0.f);
      }
      if (MODE == 2) v += resid[(long long)m * 256 + n];
      if (MODE == 3) {
        const int bb = m >> 10, nn = m & 1023, h = n & 3, d = n >> 2;
        Cout[(((long long)bb * 4 + h) * 1024 + nn) * 64 + d] = v;
      } else {
        Cout[(long long)m * ldc + n] = v;
      }
    }
  }
}

// -------------------------------------------------- flash-style attention
__global__ __launch_bounds__(256) void k_attn(
    const float* __restrict__ Q, const float* __restrict__ K,
    const float* __restrict__ V, const float* __restrict__ maskf,
    float* __restrict__ Out) {
  const int qt = blockIdx.x, h = blockIdx.y, bb = blockIdx.z;
  const int t = threadIdx.x;
  const int nl = t >> 3;  // query in tile (0..31)
  const int j8 = t & 7;   // key/dim slice
  __shared__ float Qs[32][65];
  __shared__ float Ks[64][65];
  __shared__ float Vs[64][65];
  __shared__ float Ps[32][65];
  __shared__ float red[32][8];
  __shared__ float mi[32], li[32], alph[32], mnew[32];
  __shared__ float qm[32], km[64];
  const long long hb = ((long long)bb * 4 + h) * 1024;
  const int q0 = qt * 32;
  for (int i = t; i < 32 * 64; i += 256) {
    int n = i >> 6, d = i & 63;
    Qs[n][d] = Q[(hb + q0 + n) * 64 + d];
  }
  if (t < 32) {
    qm[t] = maskf[bb * 1024 + q0 + t];
    mi[t] = -INFINITY;
    li[t] = 0.f;
  }
  float o[8] = {0.f, 0.f, 0.f, 0.f, 0.f, 0.f, 0.f, 0.f};
  __syncthreads();
  for (int kt = 0; kt < 16; kt++) {
    const int k0 = kt * 64;
    for (int i = t; i < 64 * 64; i += 256) {
      int m = i >> 6, d = i & 63;
      Ks[m][d] = K[(hb + k0 + m) * 64 + d];
      Vs[m][d] = V[(hb + k0 + m) * 64 + d];
    }
    if (t < 64) km[t] = maskf[bb * 1024 + k0 + t];
    __syncthreads();
    float sv[8];
#pragma unroll
    for (int mm = 0; mm < 8; mm++) sv[mm] = 0.f;
    for (int d = 0; d < 64; d++) {
      const float qv = Qs[nl][d];
#pragma unroll
      for (int mm = 0; mm < 8; mm++)
        sv[mm] = fmaf(qv, Ks[j8 * 8 + mm][d], sv[mm]);
    }
    float pmax = -INFINITY;
#pragma unroll
    for (int mm = 0; mm < 8; mm++) {
      float s = sv[mm] * 0.125f;
      if (qm[nl] * km[j8 * 8 + mm] == 0.f) s = -1e9f;
      sv[mm] = s;
      pmax = fmaxf(pmax, s);
    }
    red[nl][j8] = pmax;
    __syncthreads();
    if (j8 == 0) {
      float tm = red[nl][0];
#pragma unroll
      for (int i = 1; i < 8; i++) tm = fmaxf(tm, red[nl][i]);
      float nm = fmaxf(mi[nl], tm);
      alph[nl] = expf(mi[nl] - nm);  // expf(-inf)=0 on first tile
      mnew[nl] = nm;
    }
    __syncthreads();
    const float nm = mnew[nl], al = alph[nl];
    float psum = 0.f;
#pragma unroll
    for (int mm = 0; mm < 8; mm++) {
      float p = expf(sv[mm] - nm);
      Ps[nl][j8 * 8 + mm] = p;
      psum += p;
    }
    red[nl][j8] = psum;
#pragma unroll
    for (int dd = 0; dd < 8; dd++) o[dd] *= al;
    __syncthreads();
    for (int m = 0; m < 64; m++) {
      const float p = Ps[nl][m];
#pragma unroll
      for (int dd = 0; dd < 8; dd++)
        o[dd] = fmaf(p, Vs[m][j8 * 8 + dd], o[dd]);
    }
    if (j8 == 0) {
      float s = red[nl][0];
#pragma unroll
      for (int i = 1; i < 8; i++) s += red[nl][i];
      li[nl] = li[nl] * al + s;
      mi[nl] = mnew[nl];
    }
    __syncthreads();
  }
  const float inv = 1.f / li[nl];
  const long long orow = ((long long)bb * 1024 + q0 + nl) * 256;
#pragma unroll
  for (int dd = 0; dd < 8; dd++)
    Out[orow + (long long)(j8 * 8 + dd) * 4 + h] = o[dd] * inv;
}

__global__ void k_border(float* __restrict__ C, const void* __restrict__ alpha,
                         const int* __restrict__ flagp) {
  const int f = *flagp;
  int g = blockIdx.x * 256 + threadIdx.x;
  if (g >= 4 * 2050) return;
  float a = ldin(alpha, 0, f);
  int bb = g / 2050, r = g % 2050;
  float* Cb = C + (long long)bb * 1050625;
  if (r < 1025) Cb[(long long)1024 * 1025 + r] = a;
  else Cb[(long long)(r - 1025) * 1025 + 1024] = a;
}

// -------------------------------------------------------------- Sinkhorn
// C symmetric -> u- and v-sweeps are both row sweeps over the SAME rows.
// Each wave holds its rows' C entries in registers for all 200 sweeps.
DEV void gbar(unsigned* c, unsigned nblk) {
  __syncthreads();
  if (threadIdx.x == 0) {
    __hip_atomic_fetch_add(c, 1u, __ATOMIC_RELEASE, __HIP_MEMORY_SCOPE_AGENT);
    while (__hip_atomic_load(c, __ATOMIC_ACQUIRE, __HIP_MEMORY_SCOPE_AGENT) < nblk)
      __builtin_amdgcn_s_sleep(2);
  }
  __syncthreads();
}

DEV void lse_row(const float* __restrict__ c, const float* __restrict__ sv,
                 int lane, int n, float* dst) {
  float vals[17];
  float mx = -INFINITY;
#pragma unroll
  for (int i = 0; i < 17; i++) {
    int col = (i << 6) + lane;
    float x = c[i] + sv[col <= 1024 ? col : 0];  // invalid c[i] = -inf
    vals[i] = x;
    mx = fmaxf(mx, x);
  }
#pragma unroll
  for (int off = 32; off; off >>= 1) mx = fmaxf(mx, __shfl_xor(mx, off, 64));
  float s = 0.f;
#pragma unroll
  for (int i = 0; i < 17; i++) s += __expf(vals[i] - mx);
#pragma unroll
  for (int off = 32; off; off >>= 1) s += __shfl_xor(s, off, 64);
  if (lane == 0) {
    const float NORM = -7.624619086159398f;  // -log(2048)
    const float BIN = -0.6931471805599453f;  // log(1024)-log(2048)
    float lmu = (n < 1024) ? NORM : BIN;
    __hip_atomic_store(dst + n, lmu - (mx + __logf(s)), __ATOMIC_RELAXED,
                       __HIP_MEMORY_SCOPE_AGENT);
  }
}

__global__ __launch_bounds__(512) void k_sinkhorn(
    const float* __restrict__ C, float* u, float* v, unsigned* ctr,
    void* __restrict__ outv, const int* __restrict__ flagp) {
  const int f = *flagp;
  const int bb = blockIdx.x >> 6;
  const int blk = blockIdx.x & 63;
  const int t = threadIdx.x;
  const int w = (blk << 3) | (t >> 6);  // wave 0..511 within group
  const int lane = t & 63;
  const float* Cb = C + (long long)bb * 1050625;
  float* ub = u + bb * 1025;
  float* vb = v + bb * 1025;
  unsigned* cg = ctr + bb * 256;
  __shared__ float sv[1025];
  __shared__ float su[1025];
  const int rA = 2 * w, rB = 2 * w + 1;
  const bool hasC = (w == 511);
  float cA[17], cB[17], cC[17];
#pragma unroll
  for (int i = 0; i < 17; i++) {
    int col = (i << 6) + lane;
    bool ok = col <= 1024;
    cA[i] = ok ? Cb[(long long)rA * 1025 + col] : -INFINITY;
    cB[i] = ok ? Cb[(long long)rB * 1025 + col] : -INFINITY;
    cC[i] = (ok && hasC) ? Cb[(long long)1024 * 1025 + col] : -INFINITY;
  }
  for (int half = 0; half < 200; half++) {
    float* src = (half & 1) ? ub : vb;
    float* dst = (half & 1) ? vb : ub;
    for (int i = t; i < 1025; i += 512)
      sv[i] = __hip_atomic_load(src + i, __ATOMIC_RELAXED, __HIP_MEMORY_SCOPE_AGENT);
    __syncthreads();
    lse_row(cA, sv, lane, rA, dst);
    lse_row(cB, sv, lane, rB, dst);
    if (hasC) lse_row(cC, sv, lane, 1024, dst);
    gbar(cg + half, 64u);
  }
  for (int i = t; i < 1025; i += 512) {
    su[i] = __hip_atomic_load(ub + i, __ATOMIC_RELAXED, __HIP_MEMORY_SCOPE_AGENT);
    sv[i] = __hip_atomic_load(vb + i, __ATOMIC_RELAXED, __HIP_MEMORY_SCOPE_AGENT);
  }
  __syncthreads();
  const float NORM = -7.624619086159398f;
  const long long base = (long long)bb * 1050625;
#pragma unroll
  for (int rr = 0; rr < 3; rr++) {
    int n = (rr == 0) ? rA : (rr == 1) ? rB : 1024;
    const float* c = (rr == 0) ? cA : (rr == 1) ? cB : cC;
    if (rr == 2 && !hasC) break;
    float un = su[n];
#pragma unroll
    for (int i = 0; i < 17; i++) {
      int col = (i << 6) + lane;
      if (col <= 1024) {
        float val = c[i] + un + sv[col] - NORM;
        if (f) ((float*)outv)[base + (long long)n * 1025 + col] = val;
        else ((bf16*)outv)[base + (long long)n * 1025 + col] = __float2bfloat16(val);
      }
    }
  }
}

// ================================================================== launch
extern "C" void kernel_launch(void* const* d_in, const int* in_sizes, int n_in,
                              void* d_out, int out_size, void* d_ws, size_t ws_size,
                              hipStream_t stream) {
  const void* scores = d_in[0];
  const void* distance = d_in[1];
  const void* enc_W0 = d_in[2];
  const void* enc_b0 = d_in[3];
  const void* enc_bn = d_in[4];
  const void* enc_W1 = d_in[5];
  const void* enc_b1 = d_in[6];
  const void* gnn_Wqkv = d_in[7];
  const void* gnn_bqkv = d_in[8];
  const void* gnn_Wm = d_in[9];
  const void* gnn_bm = d_in[10];
  const void* gnn_W1 = d_in[11];
  const void* gnn_b1 = d_in[12];
  const void* gnn_bn = d_in[13];
  const void* gnn_W2 = d_in[14];
  const void* gnn_b2 = d_in[15];
  const void* final_W = d_in[16];
  const void* final_b = d_in[17];
  const void* alpha = d_in[18];
  (void)in_sizes; (void)n_in; (void)out_size; (void)ws_size;

  char* ws = (char*)d_ws;
  size_t off = 0;
  auto alloc = [&](size_t bytes) -> void* {
    void* p = ws + off;
    off += (bytes + 255) & ~(size_t)255;
    return p;
  };
  int* flag = (int*)alloc(256);
  float* sn = (float*)alloc(20000 * 4);
  int* idxO = (int*)alloc(4096 * 4);
  float* valsO = (float*)alloc(4096 * 4);
  float* maskO = (float*)alloc(4096 * 4);
  float* emb = (float*)alloc((size_t)4096 * 235 * 4);
  float* T0 = (float*)alloc((size_t)4096 * 256 * 4);
  float* X = (float*)alloc((size_t)4096 * 256 * 4);
  float* Qh = (float*)alloc((size_t)4096 * 256 * 4);
  float* Kh = (float*)alloc((size_t)4096 * 256 * 4);
  float* Vh = (float*)alloc((size_t)4096 * 256 * 4);
  float* msgb = (float*)alloc((size_t)4096 * 256 * 4);
  float* M2 = (float*)alloc((size_t)4096 * 256 * 4);
  float* Y1 = (float*)alloc((size_t)4096 * 512 * 4);
  float* MD = (float*)alloc((size_t)4096 * 256 * 4);
  float* Cpl = (float*)alloc((size_t)4 * 1050625 * 4);
  float* u = (float*)alloc(4100 * 4);
  float* v = (float*)alloc(4100 * 4);
  unsigned* ctr = (unsigned*)alloc(4 * 256 * 4);

  hipMemsetAsync(u, 0, 4100 * 4, stream);
  hipMemsetAsync(v, 0, 4100 * 4, stream);
  hipMemsetAsync(ctr, 0, 4 * 256 * 4, stream);

  const dim3 b256(256);
  k_detect<<<1, b256, 0, stream>>>(distance, flag);
  k_nms<<<4, 512, 0, stream>>>(scores, flag, sn);
  k_sort<<<4, 1024, 0, stream>>>(sn, idxO, valsO, maskO);
  k_emb<<<4096, b256, 0, stream>>>(idxO, valsO, distance, emb, flag);

  // encoder: relu(bn(emb@W0^T+b0)) then @W1^T+b1
  gemm_nt<1, true, false><<<dim3(4, 128, 1), b256, 0, stream>>>(
      emb, nullptr, 235, enc_W0, enc_b0, enc_bn, nullptr, T0, 256, 4096, 256, 235,
      1.f, 0, 0, 0, 0, 0, 0, flag);
  gemm_nt<0, true, false><<<dim3(4, 128, 1), b256, 0, stream>>>(
      T0, nullptr, 256, enc_W1, enc_b1, nullptr, nullptr, X, 256, 4096, 256, 256,
      1.f, 0, 0, 0, 0, 0, 0, flag);

  for (int l = 0; l < 4; l++) {
    for (int qkv = 0; qkv < 3; qkv++) {
      float* dstq = (qkv == 0) ? Qh : (qkv == 1) ? Kh : Vh;
      gemm_nt<3, true, false><<<dim3(4, 128, 1), b256, 0, stream>>>(
          X, nullptr, 256, gnn_Wqkv, gnn_bqkv, nullptr, nullptr, dstq, 0, 4096,
          256, 256, 1.f, 0, 0, 0, (long long)(l * 3 + qkv) * 65536,
          (long long)(l * 3 + qkv) * 256, 0, flag);
    }
    k_attn<<<dim3(32, 4, 4), b256, 0, stream>>>(Qh, Kh, Vh, maskO, msgb);
    gemm_nt<0, true, false><<<dim3(4, 128, 1), b256, 0, stream>>>(
        msgb, nullptr, 256, gnn_Wm, gnn_bm, nullptr, nullptr, M2, 256, 4096, 256,
        256, 1.f, 0, 0, 0, (long long)l * 65536, (long long)l * 256, 0, flag);
    gemm_nt<1, true, true><<<dim3(8, 128, 1), b256, 0, stream>>>(
        X, M2, 256, gnn_W1, gnn_b1, gnn_bn, nullptr, Y1, 512, 4096, 512, 512, 1.f,
        0, 0, 0, (long long)l * 262144, (long long)l * 512, (long long)l * 2048, flag);
    gemm_nt<2, true, false><<<dim3(4, 128, 1), b256, 0, stream>>>(
        Y1, nullptr, 512, gnn_W2, gnn_b2, nullptr, X, X, 256, 4096, 256, 512, 1.f,
        0, 0, 0, (long long)l * 131072, (long long)l * 256, 0, flag);
  }
  gemm_nt<0, true, false><<<dim3(4, 128, 1), b256, 0, stream>>>(
      X, nullptr, 256, final_W, final_b, nullptr, nullptr, MD, 256, 4096, 256, 256,
      1.f, 0, 0, 0, 0, 0, 0, flag);
  // Gram: sc = (MD_b @ MD_b^T)/16 into inner 1024x1024 of couplings (ldc=1025)
  gemm_nt<4, false, false><<<dim3(16, 32, 4), b256, 0, stream>>>(
      MD, nullptr, 256, MD, nullptr, nullptr, nullptr, Cpl, 1025, 1024, 1024, 256,
      0.0625f, 262144, 262144, 1050625, 0, 0, 0, flag);
  k_border<<<33, b256, 0, stream>>>(Cpl, alpha, flag);
  k_sinkhorn<<<256, 512, 0, stream>>>(Cpl, u, v, ctr, d_out, flag);
}

// Round 4
// 4475.679 us; speedup vs baseline: 1.5025x; 1.3397x over previous
//
#include <hip/hip_runtime.h>
#include <hip/hip_bf16.h>

typedef __hip_bfloat16 bf16;
#define DEV __device__ __forceinline__

// Adaptive input load: flag==1 -> fp32 data, flag==0 -> bf16 data.
DEV float ldin(const void* p, long long i, int f) {
  return f ? ((const float*)p)[i]
           : __uint_as_float(((unsigned)((const unsigned short*)p)[i]) << 16);
}
DEV float4 ldw4(const void* W, long long idx, int wf) {
  if (wf) return *(const float4*)((const float*)W + idx);
  ushort4 r = *(const ushort4*)((const unsigned short*)W + idx);
  return make_float4(__uint_as_float((unsigned)r.x << 16),
                     __uint_as_float((unsigned)r.y << 16),
                     __uint_as_float((unsigned)r.z << 16),
                     __uint_as_float((unsigned)r.w << 16));
}

// ------------------------------------------------------------ dtype detector
__global__ void k_detect(const void* __restrict__ dist, int* __restrict__ flag) {
  const unsigned short* p = (const unsigned short*)dist;
  __shared__ int bad;
  if (threadIdx.x == 0) bad = 0;
  __syncthreads();
  int cnt = 0;
  for (int i = threadIdx.x; i < 65536; i += 256) {
    unsigned e = (p[i] >> 7) & 0xFF;
    if (e >= 0x86) cnt++;
  }
  atomicAdd(&bad, cnt);
  __syncthreads();
  if (threadIdx.x == 0) *flag = (bad > 100) ? 1 : 0;
}

// ------------------------------------------------- fused NMS (one block/batch)
DEV void mp5_sep(const float* in, float* tmp, float* out, int t) {
  for (int i = t; i < 5000; i += 512) {
    int y = i / 100, x = i % 100;
    int x0 = x - 2 < 0 ? 0 : x - 2, x1 = x + 2 > 99 ? 99 : x + 2;
    float m = -INFINITY;
    for (int xx = x0; xx <= x1; xx++) m = fmaxf(m, in[y * 100 + xx]);
    tmp[i] = m;
  }
  __syncthreads();
  for (int i = t; i < 5000; i += 512) {
    int y = i / 100, x = i % 100;
    int y0 = y - 2 < 0 ? 0 : y - 2, y1 = y + 2 > 49 ? 49 : y + 2;
    float m = -INFINITY;
    for (int yy = y0; yy <= y1; yy++) m = fmaxf(m, tmp[yy * 100 + x]);
    out[i] = m;
  }
  __syncthreads();
}

__global__ __launch_bounds__(512) void k_nms(const void* __restrict__ scores,
                                             const int* __restrict__ flagp,
                                             float* __restrict__ sn) {
  const int f = *flagp;
  const int bb = blockIdx.x, t = threadIdx.x;
  __shared__ float S[5000], T[5000], P[5000], MK[5000], SP[5000], SS[5000];
  for (int i = t; i < 5000; i += 512) S[i] = ldin(scores, bb * 5000 + i, f);
  __syncthreads();
  mp5_sep(S, T, P, t);
  for (int i = t; i < 5000; i += 512) MK[i] = (S[i] == P[i]) ? 1.f : 0.f;
  __syncthreads();
  for (int r = 0; r < 2; r++) {
    mp5_sep(MK, T, P, t);
    for (int i = t; i < 5000; i += 512) {
      SP[i] = (P[i] > 0.f) ? 1.f : 0.f;
      SS[i] = (SP[i] != 0.f) ? 0.f : S[i];
    }
    __syncthreads();
    mp5_sep(SS, T, P, t);
    for (int i = t; i < 5000; i += 512)
      if (MK[i] == 0.f) MK[i] = ((SS[i] == P[i]) && (SP[i] == 0.f)) ? 1.f : 0.f;
    __syncthreads();
  }
  for (int i = t; i < 5000; i += 512)
    sn[bb * 5000 + i] = (MK[i] != 0.f) ? S[i] : 0.f;
}

// ------------------------------------------------ exact top-k via bitonic sort
__global__ __launch_bounds__(1024) void k_sort(
    const float* __restrict__ sn,
    int* __restrict__ idxO, float* __restrict__ valsO, float* __restrict__ maskO) {
  __shared__ unsigned long long keys[8192];
  const int bb = blockIdx.x;
  const int t = threadIdx.x;
  for (int i = t; i < 8192; i += 1024) {
    unsigned long long kk;
    if (i < 5000) {
      float v = sn[bb * 5000 + i];
      unsigned vb = __float_as_uint(v);  // scores >= 0 -> monotone bits
      kk = ((unsigned long long)vb << 32) | (unsigned)(0xFFFFFFFFu - (unsigned)i);
    } else {
      kk = 0ull;
    }
    keys[i] = ~kk;
  }
  __syncthreads();
  for (int k = 2; k <= 8192; k <<= 1) {
    for (int j = k >> 1; j > 0; j >>= 1) {
      for (int i = t; i < 8192; i += 1024) {
        int ixj = i ^ j;
        if (ixj > i) {
          unsigned long long a = keys[i], b = keys[ixj];
          bool up = ((i & k) == 0);
          if (up ? (a > b) : (a < b)) { keys[i] = b; keys[ixj] = a; }
        }
      }
      __syncthreads();
    }
  }
  {
    unsigned long long kk = ~keys[t];
    unsigned idx = 0xFFFFFFFFu - (unsigned)(kk & 0xFFFFFFFFu);
    float v = __uint_as_float((unsigned)(kk >> 32));
    idxO[bb * 1024 + t] = (int)idx;
    valsO[bb * 1024 + t] = v;
    maskO[bb * 1024 + t] = (v > 0.015f) ? 1.f : 0.f;
  }
}

// --------------------------------------------------------- embedding build
// emb padded to 256 cols (235..255 zero) so GEMM K=256 aligned.
__global__ void k_emb(const int* __restrict__ idxO, const float* __restrict__ valsO,
                      const void* __restrict__ distance, float* __restrict__ emb,
                      const int* __restrict__ flagp) {
  const int f = *flagp;
  const int vtx = blockIdx.x;
  const int bb = vtx >> 10, i = vtx & 1023;
  const int t = threadIdx.x;
  const int id = idxO[bb * 1024 + i];
  const int cy = id / 100, cx = id % 100;
  const float nvx = ((float)cx - 50.0f + 0.5f) / 100.0f;
  const float nvy = ((float)cy - 25.0f + 0.5f) / 50.0f;
  float* e = emb + (long long)vtx * 256;
  for (int c = t; c < 256; c += 256) {
    float val;
    if (c == 0) val = nvx;
    else if (c == 1) val = nvy;
    else if (c < 42) {
      int d = c - 2, fq = d >> 2, r = d & 3;
      float freq = (float)(1 << fq);
      float ang = ((r == 0 || r == 2) ? nvx : nvy) * freq;
      val = (r < 2) ? sinf(ang) : cosf(ang);
    } else if (c == 42) {
      val = valsO[bb * 1024 + i];
    } else if (c < 235) {
      int d = c - 43, cls = d >> 6, ii = (d >> 3) & 7, jj = d & 7;
      val = ldin(distance,
                 (((long long)bb * 3 + cls) * 400 + (cy * 8 + ii)) * 800 + (cx * 8 + jj), f);
    } else {
      val = 0.f;
    }
    e[c] = val;
  }
}

// --------------------------------------------- pad enc_W0 [256][235]->[256][256]
__global__ void k_padw0(const void* __restrict__ W0, float* __restrict__ Wp,
                        const int* __restrict__ flagp) {
  const int f = *flagp;
  int i = blockIdx.x * 256 + threadIdx.x;
  int r = i >> 8, c = i & 255;
  Wp[i] = (c < 235) ? ldin(W0, (long long)r * 235 + c, f) : 0.f;
}

// ----------------------------------------------------------------- GEMM (NT)
// out[m,n] = sum_k A[m,k]*W[n,k] (+epilogue). Tile BM x 64, BK=32, 256 thr,
// register-prefetch pipeline. MODE: 0 +bias; 1 +bias,BN,ReLU; 2 +bias+resid
// (in-place on Cout); 3 +bias, permuted QKV store; 4 *scale (Gram, ldc=1025).
// WF=1: W is fp32 workspace; WF=0: W dtype per runtime flag.
template <int MODE, bool SPLIT, int WF, int BM>
__global__ __launch_bounds__(256) void gemm_nt(
    const float* __restrict__ A, const float* __restrict__ A2, int lda,
    const void* __restrict__ W, const void* __restrict__ bias,
    const void* __restrict__ bn, float* __restrict__ Cout, int ldc,
    int N, int K, float scale,
    long long aBatch, long long wBatch, long long cBatch,
    long long wOff, long long bOff, long long bnOff,
    const int* __restrict__ flagp) {
  const int rf = *flagp;
  const int wf = WF ? 1 : rf;
  A += (long long)blockIdx.z * aBatch;
  const long long wbase = wOff + (long long)blockIdx.z * wBatch;
  Cout += (long long)blockIdx.z * cBatch;
  constexpr int RM = BM / 16;
  constexpr int LA = BM / 32;  // float4 A-loads per thread
  __shared__ float As[32][BM + 4];
  __shared__ float Bs[32][68];
  const int t = threadIdx.x;
  const int m0 = blockIdx.y * BM, n0 = blockIdx.x * 64;
  const int tx = t & 15, ty = t >> 4;
  float4 ar[LA], br[2];
  auto loadT = [&](int k0) {
#pragma unroll
    for (int i = 0; i < LA; i++) {
      int id = t + i * 256;
      int m = id >> 3, k4 = (id & 7) << 2;
      const float* Ap = A;
      int kc = k0 + k4;
      if (SPLIT && kc >= 256) { Ap = A2; kc -= 256; }
      ar[i] = *(const float4*)&Ap[(long long)(m0 + m) * (SPLIT ? 256 : lda) + kc];
    }
#pragma unroll
    for (int i = 0; i < 2; i++) {
      int id = t + i * 256;
      int n = id >> 3, k4 = (id & 7) << 2;
      br[i] = ldw4(W, wbase + (long long)(n0 + n) * K + k0 + k4, wf);
    }
  };
  auto storeT = [&]() {
#pragma unroll
    for (int i = 0; i < LA; i++) {
      int id = t + i * 256;
      int m = id >> 3, k4 = (id & 7) << 2;
      As[k4][m] = ar[i].x; As[k4 + 1][m] = ar[i].y;
      As[k4 + 2][m] = ar[i].z; As[k4 + 3][m] = ar[i].w;
    }
#pragma unroll
    for (int i = 0; i < 2; i++) {
      int id = t + i * 256;
      int n = id >> 3, k4 = (id & 7) << 2;
      Bs[k4][n] = br[i].x; Bs[k4 + 1][n] = br[i].y;
      Bs[k4 + 2][n] = br[i].z; Bs[k4 + 3][n] = br[i].w;
    }
  };
  float acc[RM][4];
#pragma unroll
  for (int i = 0; i < RM; i++)
#pragma unroll
    for (int j = 0; j < 4; j++) acc[i][j] = 0.f;
  loadT(0);
  for (int k0 = 0; k0 < K; k0 += 32) {
    storeT();
    __syncthreads();
    if (k0 + 32 < K) loadT(k0 + 32);
#pragma unroll
    for (int kk = 0; kk < 32; kk++) {
      float4 b4 = *(const float4*)&Bs[kk][tx << 2];
#pragma unroll
      for (int i4 = 0; i4 < RM / 4; i4++) {
        float4 a4 = *(const float4*)&As[kk][ty * RM + i4 * 4];
        const float av[4] = {a4.x, a4.y, a4.z, a4.w};
#pragma unroll
        for (int ii = 0; ii < 4; ii++) {
          int r = i4 * 4 + ii;
          acc[r][0] = fmaf(av[ii], b4.x, acc[r][0]);
          acc[r][1] = fmaf(av[ii], b4.y, acc[r][1]);
          acc[r][2] = fmaf(av[ii], b4.z, acc[r][2]);
          acc[r][3] = fmaf(av[ii], b4.w, acc[r][3]);
        }
      }
    }
    __syncthreads();
  }
#pragma unroll
  for (int r = 0; r < RM; r++) {
    const int m = m0 + ty * RM + r;
    float vv[4];
#pragma unroll
    for (int jj = 0; jj < 4; jj++) {
      const int n = n0 + (tx << 2) + jj;
      float v = acc[r][jj];
      if (MODE == 4) v *= scale;
      else v += ldin(bias, bOff + n, rf);
      if (MODE == 1) {
        const float g = ldin(bn, bnOff + n, rf);
        const float bt = ldin(bn, bnOff + N + n, rf);
        const float mu = ldin(bn, bnOff + 2 * N + n, rf);
        const float vr = ldin(bn, bnOff + 3 * N + n, rf);
        v = g * (v - mu) / sqrtf(vr + 1e-5f) + bt;
        v = fmaxf(v, 0.f);
      }
      vv[jj] = v;
    }
    if (MODE == 2) {
      float4 rs = *(const float4*)&Cout[(long long)m * ldc + n0 + (tx << 2)];
      vv[0] += rs.x; vv[1] += rs.y; vv[2] += rs.z; vv[3] += rs.w;
    }
    if (MODE == 3) {
#pragma unroll
      for (int jj = 0; jj < 4; jj++) {
        int n = n0 + (tx << 2) + jj;
        int qkv = n >> 8, c = n & 255, h = c & 3, d = c >> 2;
        int bb2 = m >> 10, nn = m & 1023;
        Cout[(long long)qkv * 4194304 +
             (((long long)(bb2 * 4 + h)) * 1024 + nn) * 64 + d] = vv[jj];
      }
    } else if (MODE == 4) {
#pragma unroll
      for (int jj = 0; jj < 4; jj++)
        Cout[(long long)m * ldc + n0 + (tx << 2) + jj] = vv[jj];
    } else {
      *(float4*)&Cout[(long long)m * ldc + n0 + (tx << 2)] =
          make_float4(vv[0], vv[1], vv[2], vv[3]);
    }
  }
}

// -------------------------------------------------- flash-style attention
// q-tile 64, k-tile 64; thread (q2=t>>3, j8=t&7) owns 2 q-rows x 8 keys/dims.
// Qst/Kst d-major for b64/b128 fragment reads; Vs/Pst row-major vectorized.
__global__ __launch_bounds__(256) void k_attn(
    const float* __restrict__ QKV, const float* __restrict__ maskf,
    float* __restrict__ Out) {
  const int qt = blockIdx.x, h = blockIdx.y, bb = blockIdx.z;
  const int t = threadIdx.x;
  const int q2 = t >> 3, j8 = t & 7;
  __shared__ float Qst[64][68];
  __shared__ float Kst[64][68];
  __shared__ float Vs[64][72];
  __shared__ float Pst[64][68];
  __shared__ float qm[64], km[64];
  const float* Q = QKV;
  const float* K = QKV + 4194304;
  const float* V = QKV + 8388608;
  const long long hb = ((long long)bb * 4 + h) * 1024;
  const int q0 = qt * 64;
#pragma unroll
  for (int i = 0; i < 4; i++) {
    int id = t + i * 256;
    int q = id >> 4, d4 = (id & 15) << 2;
    float4 qv = *(const float4*)&Q[(hb + q0 + q) * 64 + d4];
    Qst[d4][q] = qv.x; Qst[d4 + 1][q] = qv.y;
    Qst[d4 + 2][q] = qv.z; Qst[d4 + 3][q] = qv.w;
  }
  if (t < 64) qm[t] = maskf[bb * 1024 + q0 + t];
  float mi[2] = {-INFINITY, -INFINITY};
  float li[2] = {0.f, 0.f};
  float o[2][8] = {};
  __syncthreads();
  const float qmr[2] = {qm[2 * q2], qm[2 * q2 + 1]};
  for (int kt = 0; kt < 16; kt++) {
    const int k0 = kt * 64;
    __syncthreads();  // prev PV done before restage
#pragma unroll
    for (int i = 0; i < 4; i++) {
      int id = t + i * 256;
      int n = id >> 4, d4 = (id & 15) << 2;
      float4 kv = *(const float4*)&K[(hb + k0 + n) * 64 + d4];
      Kst[d4][n] = kv.x; Kst[d4 + 1][n] = kv.y;
      Kst[d4 + 2][n] = kv.z; Kst[d4 + 3][n] = kv.w;
      float4 vvv = *(const float4*)&V[(hb + k0 + n) * 64 + d4];
      *(float4*)&Vs[n][d4] = vvv;
    }
    if (t < 64) km[t] = maskf[bb * 1024 + k0 + t];
    __syncthreads();
    float kmr[8];
#pragma unroll
    for (int kk = 0; kk < 8; kk++) kmr[kk] = km[8 * j8 + kk];
    float s[2][8] = {};
    for (int d = 0; d < 64; d++) {
      float2 qv = *(const float2*)&Qst[d][2 * q2];
      float4 ka = *(const float4*)&Kst[d][8 * j8];
      float4 kb = *(const float4*)&Kst[d][8 * j8 + 4];
      s[0][0] = fmaf(qv.x, ka.x, s[0][0]); s[0][1] = fmaf(qv.x, ka.y, s[0][1]);
      s[0][2] = fmaf(qv.x, ka.z, s[0][2]); s[0][3] = fmaf(qv.x, ka.w, s[0][3]);
      s[0][4] = fmaf(qv.x, kb.x, s[0][4]); s[0][5] = fmaf(qv.x, kb.y, s[0][5]);
      s[0][6] = fmaf(qv.x, kb.z, s[0][6]); s[0][7] = fmaf(qv.x, kb.w, s[0][7]);
      s[1][0] = fmaf(qv.y, ka.x, s[1][0]); s[1][1] = fmaf(qv.y, ka.y, s[1][1]);
      s[1][2] = fmaf(qv.y, ka.z, s[1][2]); s[1][3] = fmaf(qv.y, ka.w, s[1][3]);
      s[1][4] = fmaf(qv.y, kb.x, s[1][4]); s[1][5] = fmaf(qv.y, kb.y, s[1][5]);
      s[1][6] = fmaf(qv.y, kb.z, s[1][6]); s[1][7] = fmaf(qv.y, kb.w, s[1][7]);
    }
#pragma unroll
    for (int qq = 0; qq < 2; qq++) {
      float rm = -INFINITY;
#pragma unroll
      for (int kk = 0; kk < 8; kk++) {
        float val = (qmr[qq] * kmr[kk] == 0.f) ? -1e9f : s[qq][kk] * 0.125f;
        s[qq][kk] = val;
        rm = fmaxf(rm, val);
      }
      rm = fmaxf(rm, __shfl_xor(rm, 1));
      rm = fmaxf(rm, __shfl_xor(rm, 2));
      rm = fmaxf(rm, __shfl_xor(rm, 4));
      float nm = fmaxf(mi[qq], rm);
      float al = __expf(mi[qq] - nm);  // expf(-inf)=0 first tile
      mi[qq] = nm;
      float sum = 0.f;
#pragma unroll
      for (int kk = 0; kk < 8; kk++) {
        float p = __expf(s[qq][kk] - nm);
        Pst[8 * j8 + kk][2 * q2 + qq] = p;
        sum += p;
      }
      sum += __shfl_xor(sum, 1);
      sum += __shfl_xor(sum, 2);
      sum += __shfl_xor(sum, 4);
      li[qq] = li[qq] * al + sum;
#pragma unroll
      for (int dd = 0; dd < 8; dd++) o[qq][dd] *= al;
    }
    __syncthreads();
    for (int m = 0; m < 64; m++) {
      float2 pv = *(const float2*)&Pst[m][2 * q2];
      float4 va = *(const float4*)&Vs[m][8 * j8];
      float4 vb = *(const float4*)&Vs[m][8 * j8 + 4];
      o[0][0] = fmaf(pv.x, va.x, o[0][0]); o[0][1] = fmaf(pv.x, va.y, o[0][1]);
      o[0][2] = fmaf(pv.x, va.z, o[0][2]); o[0][3] = fmaf(pv.x, va.w, o[0][3]);
      o[0][4] = fmaf(pv.x, vb.x, o[0][4]); o[0][5] = fmaf(pv.x, vb.y, o[0][5]);
      o[0][6] = fmaf(pv.x, vb.z, o[0][6]); o[0][7] = fmaf(pv.x, vb.w, o[0][7]);
      o[1][0] = fmaf(pv.y, va.x, o[1][0]); o[1][1] = fmaf(pv.y, va.y, o[1][1]);
      o[1][2] = fmaf(pv.y, va.z, o[1][2]); o[1][3] = fmaf(pv.y, va.w, o[1][3]);
      o[1][4] = fmaf(pv.y, vb.x, o[1][4]); o[1][5] = fmaf(pv.y, vb.y, o[1][5]);
      o[1][6] = fmaf(pv.y, vb.z, o[1][6]); o[1][7] = fmaf(pv.y, vb.w, o[1][7]);
    }
  }
#pragma unroll
  for (int qq = 0; qq < 2; qq++) {
    const float inv = 1.f / li[qq];
    const long long orow = ((long long)bb * 1024 + q0 + 2 * q2 + qq) * 256;
#pragma unroll
    for (int dd = 0; dd < 8; dd++)
      Out[orow + (long long)(8 * j8 + dd) * 4 + h] = o[qq][dd] * inv;
  }
}

// ------------------------------------------------------------- border (col 1024)
__global__ void k_border(float* __restrict__ C, const void* __restrict__ alpha,
                         const int* __restrict__ flagp) {
  const int f = *flagp;
  int g = blockIdx.x * 256 + threadIdx.x;
  if (g >= 4096) return;
  float a = ldin(alpha, 0, f);
  int bb = g >> 10, r = g & 1023;
  C[(long long)bb * 1050625 + (long long)r * 1025 + 1024] = a;
}

// -------------------------------------------------------------- Sinkhorn
// 4 groups x 32 blocks x 512 thr. C rows in registers (4/wave); alpha-row
// analytic. 2-level tree barrier; convergence early-exit.
__global__ __launch_bounds__(512) void k_sinkhorn(
    const float* __restrict__ C, const void* __restrict__ alphap,
    float* u, float* v, unsigned* ctrb, void* __restrict__ outv,
    const int* __restrict__ flagp) {
  const int f = *flagp;
  const int bb = blockIdx.x >> 5;
  const int blk = blockIdx.x & 31;
  const int t = threadIdx.x;
  const int wid = t >> 6, lane = t & 63;
  const int w = (blk << 3) | wid;  // 0..255
  const int r0 = w << 2;
  const float alpha = ldin(alphap, 0, f);
  const float* Cb = C + (long long)bb * 1050625;
  float* ub = u + bb * 1025;
  float* vb = v + bb * 1025;
  __shared__ float sv[1025];
  __shared__ float su[1025];
  __shared__ float wred[8];
  __shared__ int quitf;
  const float NORM = -7.624619086159398f;  // -log(2048)
  const float BIN = -0.6931471805599453f;  // log(1024)-log(2048)
  float c[4][17];
#pragma unroll
  for (int j = 0; j < 4; j++)
#pragma unroll
    for (int i = 0; i < 17; i++) {
      int col = (i << 6) + lane;
      c[j][i] = (col <= 1024) ? Cb[(long long)(r0 + j) * 1025 + col] : -INFINITY;
    }
  for (int half = 0; half < 200; half++) {
    float* src = (half & 1) ? ub : vb;
    float* dst = (half & 1) ? vb : ub;
    for (int i = t; i < 1025; i += 512)
      sv[i] = __hip_atomic_load(src + i, __ATOMIC_RELAXED, __HIP_MEMORY_SCOPE_AGENT);
    __syncthreads();
    float svr[17];
#pragma unroll
    for (int i = 0; i < 17; i++) {
      int col = (i << 6) + lane;
      svr[i] = (col <= 1024) ? sv[col] : -INFINITY;
    }
    float wd = 0.f;
#pragma unroll
    for (int j = 0; j < 4; j++) {
      const int n = r0 + j;
      float mx = -INFINITY;
#pragma unroll
      for (int i = 0; i < 17; i++) mx = fmaxf(mx, c[j][i] + svr[i]);
#pragma unroll
      for (int off = 32; off; off >>= 1) mx = fmaxf(mx, __shfl_xor(mx, off, 64));
      float s = 0.f;
#pragma unroll
      for (int i = 0; i < 17; i++) s += __expf(c[j][i] + svr[i] - mx);
#pragma unroll
      for (int off = 32; off; off >>= 1) s += __shfl_xor(s, off, 64);
      if (lane == 0) {
        float nv = NORM - (mx + __logf(s));
        float old = __hip_atomic_load(dst + n, __ATOMIC_RELAXED, __HIP_MEMORY_SCOPE_AGENT);
        wd = fmaxf(wd, fabsf(nv - old));
        __hip_atomic_store(dst + n, nv, __ATOMIC_RELAXED, __HIP_MEMORY_SCOPE_AGENT);
      }
    }
    if (w == 0) {  // alpha row: LSE = alpha + LSE(src)
      float mx = -INFINITY;
#pragma unroll
      for (int i = 0; i < 17; i++) mx = fmaxf(mx, svr[i]);
#pragma unroll
      for (int off = 32; off; off >>= 1) mx = fmaxf(mx, __shfl_xor(mx, off, 64));
      float s = 0.f;
#pragma unroll
      for (int i = 0; i < 17; i++) s += __expf(svr[i] - mx);
#pragma unroll
      for (int off = 32; off; off >>= 1) s += __shfl_xor(s, off, 64);
      if (lane == 0) {
        float nv = BIN - (alpha + mx + __logf(s));
        float old = __hip_atomic_load(dst + 1024, __ATOMIC_RELAXED, __HIP_MEMORY_SCOPE_AGENT);
        wd = fmaxf(wd, fabsf(nv - old));
        __hip_atomic_store(dst + 1024, nv, __ATOMIC_RELAXED, __HIP_MEMORY_SCOPE_AGENT);
      }
    }
    if (lane == 0) wred[wid] = wd;
    __syncthreads();
    if (t == 0) {
      float bmax = wred[0];
#pragma unroll
      for (int k = 1; k < 8; k++) bmax = fmaxf(bmax, wred[k]);
      const int idx = bb * 200 + half;
      __hip_atomic_fetch_max(ctrb + 4000 + idx, __float_as_uint(bmax),
                             __ATOMIC_RELAXED, __HIP_MEMORY_SCOPE_AGENT);
      unsigned r = __hip_atomic_fetch_add(ctrb + idx * 4 + (blk >> 3), 1u,
                                          __ATOMIC_ACQ_REL, __HIP_MEMORY_SCOPE_AGENT);
      if (r == 7)
        __hip_atomic_fetch_add(ctrb + 3200 + idx, 1u, __ATOMIC_ACQ_REL,
                               __HIP_MEMORY_SCOPE_AGENT);
      while (__hip_atomic_load(ctrb + 3200 + idx, __ATOMIC_ACQUIRE,
                               __HIP_MEMORY_SCOPE_AGENT) < 4u)
        __builtin_amdgcn_s_sleep(1);
      int q = 0;
      if ((half & 1) && half >= 39) {
        float dc = __uint_as_float(__hip_atomic_load(
            ctrb + 4000 + idx, __ATOMIC_RELAXED, __HIP_MEMORY_SCOPE_AGENT));
        float dp = __uint_as_float(__hip_atomic_load(
            ctrb + 4000 + idx - 1, __ATOMIC_RELAXED, __HIP_MEMORY_SCOPE_AGENT));
        q = (dc < 2e-5f && dp < 2e-5f) ? 1 : 0;
      }
      quitf = q;
    }
    __syncthreads();
    if (quitf) break;
  }
  for (int i = t; i < 1025; i += 512) {
    su[i] = __hip_atomic_load(ub + i, __ATOMIC_RELAXED, __HIP_MEMORY_SCOPE_AGENT);
    sv[i] = __hip_atomic_load(vb + i, __ATOMIC_RELAXED, __HIP_MEMORY_SCOPE_AGENT);
  }
  __syncthreads();
  const long long base = (long long)bb * 1050625;
#pragma unroll
  for (int j = 0; j < 4; j++) {
    const int n = r0 + j;
    const float un = su[n];
#pragma unroll
    for (int i = 0; i < 17; i++) {
      int col = (i << 6) + lane;
      if (col <= 1024) {
        float val = c[j][i] + un + sv[col] - NORM;
        if (f) ((float*)outv)[base + (long long)n * 1025 + col] = val;
        else ((bf16*)outv)[base + (long long)n * 1025 + col] = __float2bfloat16(val);
      }
    }
  }
  if (w == 0) {
    const float un = su[1024];
#pragma unroll
    for (int i = 0; i < 17; i++) {
      int col = (i << 6) + lane;
      if (col <= 1024) {
        float val = alpha + un + sv[col] - NORM;
        if (f) ((float*)outv)[base + (long long)1024 * 1025 + col] = val;
        else ((bf16*)outv)[base + (long long)1024 * 1025 + col] = __float2bfloat16(val);
      }
    }
  }
}

// ================================================================== launch
extern "C" void kernel_launch(void* const* d_in, const int* in_sizes, int n_in,
                              void* d_out, int out_size, void* d_ws, size_t ws_size,
                              hipStream_t stream) {
  const void* scores = d_in[0];
  const void* distance = d_in[1];
  const void* enc_W0 = d_in[2];
  const void* enc_b0 = d_in[3];
  const void* enc_bn = d_in[4];
  const void* enc_W1 = d_in[5];
  const void* enc_b1 = d_in[6];
  const void* gnn_Wqkv = d_in[7];
  const void* gnn_bqkv = d_in[8];
  const void* gnn_Wm = d_in[9];
  const void* gnn_bm = d_in[10];
  const void* gnn_W1 = d_in[11];
  const void* gnn_b1 = d_in[12];
  const void* gnn_bn = d_in[13];
  const void* gnn_W2 = d_in[14];
  const void* gnn_b2 = d_in[15];
  const void* final_W = d_in[16];
  const void* final_b = d_in[17];
  const void* alpha = d_in[18];
  (void)in_sizes; (void)n_in; (void)out_size; (void)ws_size;

  char* ws = (char*)d_ws;
  size_t off = 0;
  auto alloc = [&](size_t bytes) -> void* {
    void* p = ws + off;
    off += (bytes + 255) & ~(size_t)255;
    return p;
  };
  int* flag = (int*)alloc(256);
  float* sn = (float*)alloc(20000 * 4);
  int* idxO = (int*)alloc(4096 * 4);
  float* valsO = (float*)alloc(4096 * 4);
  float* maskO = (float*)alloc(4096 * 4);
  float* emb = (float*)alloc((size_t)4096 * 256 * 4);
  float* Wp = (float*)alloc((size_t)65536 * 4);
  float* T0 = (float*)alloc((size_t)4096 * 256 * 4);
  float* X = (float*)alloc((size_t)4096 * 256 * 4);
  float* QKVh = (float*)alloc((size_t)3 * 4194304 * 4);
  float* msgb = (float*)alloc((size_t)4096 * 256 * 4);
  float* M2 = (float*)alloc((size_t)4096 * 256 * 4);
  float* Y1 = (float*)alloc((size_t)4096 * 512 * 4);
  float* MD = (float*)alloc((size_t)4096 * 256 * 4);
  float* Cpl = (float*)alloc((size_t)4 * 1050625 * 4);
  float* u = (float*)alloc(4100 * 4);
  float* v = (float*)alloc(4100 * 4);
  unsigned* ctrb = (unsigned*)alloc(4800 * 4);

  hipMemsetAsync(u, 0, 4100 * 4, stream);
  hipMemsetAsync(v, 0, 4100 * 4, stream);
  hipMemsetAsync(ctrb, 0, 4800 * 4, stream);

  const dim3 b256(256);
  k_detect<<<1, b256, 0, stream>>>(distance, flag);
  k_nms<<<4, 512, 0, stream>>>(scores, flag, sn);
  k_sort<<<4, 1024, 0, stream>>>(sn, idxO, valsO, maskO);
  k_emb<<<4096, b256, 0, stream>>>(idxO, valsO, distance, emb, flag);
  k_padw0<<<256, b256, 0, stream>>>(enc_W0, Wp, flag);

  gemm_nt<1, false, 1, 64><<<dim3(4, 64, 1), b256, 0, stream>>>(
      emb, nullptr, 256, Wp, enc_b0, enc_bn, T0, 256, 256, 256, 1.f,
      0, 0, 0, 0, 0, 0, flag);
  gemm_nt<0, false, 0, 64><<<dim3(4, 64, 1), b256, 0, stream>>>(
      T0, nullptr, 256, enc_W1, enc_b1, nullptr, X, 256, 256, 256, 1.f,
      0, 0, 0, 0, 0, 0, flag);

  for (int l = 0; l < 4; l++) {
    gemm_nt<3, false, 0, 128><<<dim3(12, 32, 1), b256, 0, stream>>>(
        X, nullptr, 256, gnn_Wqkv, gnn_bqkv, nullptr, QKVh, 0, 768, 256, 1.f,
        0, 0, 0, (long long)l * 196608, (long long)l * 768, 0, flag);
    k_attn<<<dim3(16, 4, 4), b256, 0, stream>>>(QKVh, maskO, msgb);
    gemm_nt<0, false, 0, 64><<<dim3(4, 64, 1), b256, 0, stream>>>(
        msgb, nullptr, 256, gnn_Wm, gnn_bm, nullptr, M2, 256, 256, 256, 1.f,
        0, 0, 0, (long long)l * 65536, (long long)l * 256, 0, flag);
    gemm_nt<1, true, 0, 128><<<dim3(8, 32, 1), b256, 0, stream>>>(
        X, M2, 256, gnn_W1, gnn_b1, gnn_bn, Y1, 512, 512, 512, 1.f,
        0, 0, 0, (long long)l * 262144, (long long)l * 512, (long long)l * 2048, flag);
    gemm_nt<2, false, 0, 64><<<dim3(4, 64, 1), b256, 0, stream>>>(
        Y1, nullptr, 512, gnn_W2, gnn_b2, nullptr, X, 256, 256, 512, 1.f,
        0, 0, 0, (long long)l * 131072, (long long)l * 256, 0, flag);
  }
  gemm_nt<0, false, 0, 64><<<dim3(4, 64, 1), b256, 0, stream>>>(
      X, nullptr, 256, final_W, final_b, nullptr, MD, 256, 256, 256, 1.f,
      0, 0, 0, 0, 0, 0, flag);
  gemm_nt<4, false, 1, 128><<<dim3(16, 8, 4), b256, 0, stream>>>(
      MD, nullptr, 256, MD, nullptr, nullptr, Cpl, 1025, 1024, 256, 0.0625f,
      262144, 262144, 1050625, 0, 0, 0, flag);
  k_border<<<16, b256, 0, stream>>>(Cpl, alpha, flag);
  k_sinkhorn<<<128, 512, 0, stream>>>(Cpl, alpha, u, v, ctrb, d_out, flag);
}

// Round 5
// 2428.181 us; speedup vs baseline: 2.7695x; 1.8432x over previous
//
#include <hip/hip_runtime.h>
#include <hip/hip_bf16.h>

typedef __hip_bfloat16 bf16;
#define DEV __device__ __forceinline__

// Adaptive input load: flag==1 -> fp32 data, flag==0 -> bf16 data.
DEV float ldin(const void* p, long long i, int f) {
  return f ? ((const float*)p)[i]
           : __uint_as_float(((unsigned)((const unsigned short*)p)[i]) << 16);
}
DEV float4 ldw4(const void* W, long long idx, int wf) {
  if (wf) return *(const float4*)((const float*)W + idx);
  ushort4 r = *(const ushort4*)((const unsigned short*)W + idx);
  return make_float4(__uint_as_float((unsigned)r.x << 16),
                     __uint_as_float((unsigned)r.y << 16),
                     __uint_as_float((unsigned)r.z << 16),
                     __uint_as_float((unsigned)r.w << 16));
}

// ------------------------------------------------------------ dtype detector
__global__ void k_detect(const void* __restrict__ dist, int* __restrict__ flag) {
  const unsigned short* p = (const unsigned short*)dist;
  __shared__ int bad;
  if (threadIdx.x == 0) bad = 0;
  __syncthreads();
  int cnt = 0;
  for (int i = threadIdx.x; i < 65536; i += 256) {
    unsigned e = (p[i] >> 7) & 0xFF;
    if (e >= 0x86) cnt++;
  }
  atomicAdd(&bad, cnt);
  __syncthreads();
  if (threadIdx.x == 0) *flag = (bad > 100) ? 1 : 0;
}

// ------------------------------------------------- fused NMS (one block/batch)
DEV void mp5_sep(const float* in, float* tmp, float* out, int t) {
  for (int i = t; i < 5000; i += 512) {
    int y = i / 100, x = i % 100;
    int x0 = x - 2 < 0 ? 0 : x - 2, x1 = x + 2 > 99 ? 99 : x + 2;
    float m = -INFINITY;
    for (int xx = x0; xx <= x1; xx++) m = fmaxf(m, in[y * 100 + xx]);
    tmp[i] = m;
  }
  __syncthreads();
  for (int i = t; i < 5000; i += 512) {
    int y = i / 100, x = i % 100;
    int y0 = y - 2 < 0 ? 0 : y - 2, y1 = y + 2 > 49 ? 49 : y + 2;
    float m = -INFINITY;
    for (int yy = y0; yy <= y1; yy++) m = fmaxf(m, tmp[yy * 100 + x]);
    out[i] = m;
  }
  __syncthreads();
}

__global__ __launch_bounds__(512) void k_nms(const void* __restrict__ scores,
                                             const int* __restrict__ flagp,
                                             float* __restrict__ sn) {
  const int f = *flagp;
  const int bb = blockIdx.x, t = threadIdx.x;
  __shared__ float S[5000], T[5000], P[5000], MK[5000], SP[5000], SS[5000];
  for (int i = t; i < 5000; i += 512) S[i] = ldin(scores, bb * 5000 + i, f);
  __syncthreads();
  mp5_sep(S, T, P, t);
  for (int i = t; i < 5000; i += 512) MK[i] = (S[i] == P[i]) ? 1.f : 0.f;
  __syncthreads();
  for (int r = 0; r < 2; r++) {
    mp5_sep(MK, T, P, t);
    for (int i = t; i < 5000; i += 512) {
      SP[i] = (P[i] > 0.f) ? 1.f : 0.f;
      SS[i] = (SP[i] != 0.f) ? 0.f : S[i];
    }
    __syncthreads();
    mp5_sep(SS, T, P, t);
    for (int i = t; i < 5000; i += 512)
      if (MK[i] == 0.f) MK[i] = ((SS[i] == P[i]) && (SP[i] == 0.f)) ? 1.f : 0.f;
    __syncthreads();
  }
  for (int i = t; i < 5000; i += 512)
    sn[bb * 5000 + i] = (MK[i] != 0.f) ? S[i] : 0.f;
}

// ------------------------------------------------ exact top-k via bitonic sort
// Also emits nv[bb] = count of vals > thresh (a prefix, since sorted desc).
__global__ __launch_bounds__(1024) void k_sort(
    const float* __restrict__ sn,
    int* __restrict__ idxO, float* __restrict__ valsO, float* __restrict__ maskO,
    int* __restrict__ nvp) {
  __shared__ unsigned long long keys[8192];
  __shared__ int cnt;
  const int bb = blockIdx.x;
  const int t = threadIdx.x;
  if (t == 0) cnt = 0;
  for (int i = t; i < 8192; i += 1024) {
    unsigned long long kk;
    if (i < 5000) {
      float v = sn[bb * 5000 + i];
      unsigned vb = __float_as_uint(v);  // scores >= 0 -> monotone bits
      kk = ((unsigned long long)vb << 32) | (unsigned)(0xFFFFFFFFu - (unsigned)i);
    } else {
      kk = 0ull;
    }
    keys[i] = ~kk;
  }
  __syncthreads();
  for (int k = 2; k <= 8192; k <<= 1) {
    for (int j = k >> 1; j > 0; j >>= 1) {
      for (int i = t; i < 8192; i += 1024) {
        int ixj = i ^ j;
        if (ixj > i) {
          unsigned long long a = keys[i], b = keys[ixj];
          bool up = ((i & k) == 0);
          if (up ? (a > b) : (a < b)) { keys[i] = b; keys[ixj] = a; }
        }
      }
      __syncthreads();
    }
  }
  {
    unsigned long long kk = ~keys[t];
    unsigned idx = 0xFFFFFFFFu - (unsigned)(kk & 0xFFFFFFFFu);
    float v = __uint_as_float((unsigned)(kk >> 32));
    idxO[bb * 1024 + t] = (int)idx;
    valsO[bb * 1024 + t] = v;
    bool valid = (v > 0.015f);
    maskO[bb * 1024 + t] = valid ? 1.f : 0.f;
    unsigned long long bal = __ballot(valid);
    if ((t & 63) == 0) atomicAdd(&cnt, (int)__popcll(bal));
  }
  __syncthreads();
  if (t == 0) nvp[bb] = cnt;
}

// --------------------------------------------------------- embedding build
__global__ void k_emb(const int* __restrict__ idxO, const float* __restrict__ valsO,
                      const void* __restrict__ distance, float* __restrict__ emb,
                      const int* __restrict__ flagp) {
  const int f = *flagp;
  const int vtx = blockIdx.x;
  const int bb = vtx >> 10, i = vtx & 1023;
  const int t = threadIdx.x;
  const int id = idxO[bb * 1024 + i];
  const int cy = id / 100, cx = id % 100;
  const float nvx = ((float)cx - 50.0f + 0.5f) / 100.0f;
  const float nvy = ((float)cy - 25.0f + 0.5f) / 50.0f;
  float* e = emb + (long long)vtx * 256;
  for (int c = t; c < 256; c += 256) {
    float val;
    if (c == 0) val = nvx;
    else if (c == 1) val = nvy;
    else if (c < 42) {
      int d = c - 2, fq = d >> 2, r = d & 3;
      float freq = (float)(1 << fq);
      float ang = ((r == 0 || r == 2) ? nvx : nvy) * freq;
      val = (r < 2) ? sinf(ang) : cosf(ang);
    } else if (c == 42) {
      val = valsO[bb * 1024 + i];
    } else if (c < 235) {
      int d = c - 43, cls = d >> 6, ii = (d >> 3) & 7, jj = d & 7;
      val = ldin(distance,
                 (((long long)bb * 3 + cls) * 400 + (cy * 8 + ii)) * 800 + (cx * 8 + jj), f);
    } else {
      val = 0.f;
    }
    e[c] = val;
  }
}

// --------------------------------------------- pad enc_W0 [256][235]->[256][256]
__global__ void k_padw0(const void* __restrict__ W0, float* __restrict__ Wp,
                        const int* __restrict__ flagp) {
  const int f = *flagp;
  int i = blockIdx.x * 256 + threadIdx.x;
  int r = i >> 8, c = i & 255;
  Wp[i] = (c < 235) ? ldin(W0, (long long)r * 235 + c, f) : 0.f;
}

// ----------------------------------------------------------------- GEMM (NT)
template <int MODE, bool SPLIT, int WF, int BM>
__global__ __launch_bounds__(256) void gemm_nt(
    const float* __restrict__ A, const float* __restrict__ A2, int lda,
    const void* __restrict__ W, const void* __restrict__ bias,
    const void* __restrict__ bn, float* __restrict__ Cout, int ldc,
    int N, int K, float scale,
    long long aBatch, long long wBatch, long long cBatch,
    long long wOff, long long bOff, long long bnOff,
    const int* __restrict__ flagp) {
  const int rf = *flagp;
  const int wf = WF ? 1 : rf;
  A += (long long)blockIdx.z * aBatch;
  const long long wbase = wOff + (long long)blockIdx.z * wBatch;
  Cout += (long long)blockIdx.z * cBatch;
  constexpr int RM = BM / 16;
  constexpr int LA = BM / 32;
  __shared__ float As[32][BM + 4];
  __shared__ float Bs[32][68];
  const int t = threadIdx.x;
  const int m0 = blockIdx.y * BM, n0 = blockIdx.x * 64;
  const int tx = t & 15, ty = t >> 4;
  float4 ar[LA], br[2];
  auto loadT = [&](int k0) {
#pragma unroll
    for (int i = 0; i < LA; i++) {
      int id = t + i * 256;
      int m = id >> 3, k4 = (id & 7) << 2;
      const float* Ap = A;
      int kc = k0 + k4;
      if (SPLIT && kc >= 256) { Ap = A2; kc -= 256; }
      ar[i] = *(const float4*)&Ap[(long long)(m0 + m) * (SPLIT ? 256 : lda) + kc];
    }
#pragma unroll
    for (int i = 0; i < 2; i++) {
      int id = t + i * 256;
      int n = id >> 3, k4 = (id & 7) << 2;
      br[i] = ldw4(W, wbase + (long long)(n0 + n) * K + k0 + k4, wf);
    }
  };
  auto storeT = [&]() {
#pragma unroll
    for (int i = 0; i < LA; i++) {
      int id = t + i * 256;
      int m = id >> 3, k4 = (id & 7) << 2;
      As[k4][m] = ar[i].x; As[k4 + 1][m] = ar[i].y;
      As[k4 + 2][m] = ar[i].z; As[k4 + 3][m] = ar[i].w;
    }
#pragma unroll
    for (int i = 0; i < 2; i++) {
      int id = t + i * 256;
      int n = id >> 3, k4 = (id & 7) << 2;
      Bs[k4][n] = br[i].x; Bs[k4 + 1][n] = br[i].y;
      Bs[k4 + 2][n] = br[i].z; Bs[k4 + 3][n] = br[i].w;
    }
  };
  float acc[RM][4];
#pragma unroll
  for (int i = 0; i < RM; i++)
#pragma unroll
    for (int j = 0; j < 4; j++) acc[i][j] = 0.f;
  loadT(0);
  for (int k0 = 0; k0 < K; k0 += 32) {
    storeT();
    __syncthreads();
    if (k0 + 32 < K) loadT(k0 + 32);
#pragma unroll
    for (int kk = 0; kk < 32; kk++) {
      float4 b4 = *(const float4*)&Bs[kk][tx << 2];
#pragma unroll
      for (int i4 = 0; i4 < RM / 4; i4++) {
        float4 a4 = *(const float4*)&As[kk][ty * RM + i4 * 4];
        const float av[4] = {a4.x, a4.y, a4.z, a4.w};
#pragma unroll
        for (int ii = 0; ii < 4; ii++) {
          int r = i4 * 4 + ii;
          acc[r][0] = fmaf(av[ii], b4.x, acc[r][0]);
          acc[r][1] = fmaf(av[ii], b4.y, acc[r][1]);
          acc[r][2] = fmaf(av[ii], b4.z, acc[r][2]);
          acc[r][3] = fmaf(av[ii], b4.w, acc[r][3]);
        }
      }
    }
    __syncthreads();
  }
#pragma unroll
  for (int r = 0; r < RM; r++) {
    const int m = m0 + ty * RM + r;
    float vv[4];
#pragma unroll
    for (int jj = 0; jj < 4; jj++) {
      const int n = n0 + (tx << 2) + jj;
      float v = acc[r][jj];
      if (MODE == 4) v *= scale;
      else v += ldin(bias, bOff + n, rf);
      if (MODE == 1) {
        const float g = ldin(bn, bnOff + n, rf);
        const float bt = ldin(bn, bnOff + N + n, rf);
        const float mu = ldin(bn, bnOff + 2 * N + n, rf);
        const float vr = ldin(bn, bnOff + 3 * N + n, rf);
        v = g * (v - mu) / sqrtf(vr + 1e-5f) + bt;
        v = fmaxf(v, 0.f);
      }
      vv[jj] = v;
    }
    if (MODE == 2) {
      float4 rs = *(const float4*)&Cout[(long long)m * ldc + n0 + (tx << 2)];
      vv[0] += rs.x; vv[1] += rs.y; vv[2] += rs.z; vv[3] += rs.w;
    }
    if (MODE == 3) {
#pragma unroll
      for (int jj = 0; jj < 4; jj++) {
        int n = n0 + (tx << 2) + jj;
        int qkv = n >> 8, c = n & 255, h = c & 3, d = c >> 2;
        int bb2 = m >> 10, nn = m & 1023;
        Cout[(long long)qkv * 4194304 +
             (((long long)(bb2 * 4 + h)) * 1024 + nn) * 64 + d] = vv[jj];
      }
    } else if (MODE == 4) {
#pragma unroll
      for (int jj = 0; jj < 4; jj++)
        Cout[(long long)m * ldc + n0 + (tx << 2) + jj] = vv[jj];
    } else {
      *(float4*)&Cout[(long long)m * ldc + n0 + (tx << 2)] =
          make_float4(vv[0], vv[1], vv[2], vv[3]);
    }
  }
}

// ------------------------------------------------ per-(b,h) mean of V rows
__global__ __launch_bounds__(256) void k_meanv(const float* __restrict__ QKV,
                                               float* __restrict__ meanV) {
  const int bh = blockIdx.x;  // 0..15
  const int t = threadIdx.x;
  const int c4 = t >> 6, d = t & 63;
  __shared__ float part[4][64];
  const float* V = QKV + 8388608 + (long long)bh * 65536;
  float s = 0.f;
  for (int r = c4 * 256; r < (c4 + 1) * 256; r++) s += V[r * 64 + d];
  part[c4][d] = s;
  __syncthreads();
  if (c4 == 0)
    meanV[bh * 64 + d] =
        (part[0][d] + part[1][d] + part[2][d] + part[3][d]) * (1.f / 1024.f);
}

// -------------------------------------------------- flash-style attention
// Valid mask is a prefix [0,nv): k-loop bounded by ceil(nv/64); rows >= nv
// output mean(V) exactly (uniform softmax over all 1024 keys).
__global__ __launch_bounds__(256) void k_attn(
    const float* __restrict__ QKV, const float* __restrict__ maskf,
    const int* __restrict__ nvp, const float* __restrict__ meanV,
    float* __restrict__ Out) {
  const int qt = blockIdx.x, h = blockIdx.y, bb = blockIdx.z;
  const int t = threadIdx.x;
  const int q2 = t >> 3, j8 = t & 7;
  __shared__ float Qst[64][68];
  __shared__ float Kst[64][68];
  __shared__ float Vs[64][72];
  __shared__ float Pst[64][68];
  __shared__ float qm[64], km[64];
  const float* Q = QKV;
  const float* K = QKV + 4194304;
  const float* V = QKV + 8388608;
  const long long hb = ((long long)bb * 4 + h) * 1024;
  const int q0 = qt * 64;
  const int nv = nvp[bb];
  const int nt = (nv + 63) >> 6;
  float mi[2] = {-INFINITY, -INFINITY};
  float li[2] = {0.f, 0.f};
  float o[2][8] = {};
  if (q0 < nv) {
#pragma unroll
    for (int i = 0; i < 4; i++) {
      int id = t + i * 256;
      int q = id >> 4, d4 = (id & 15) << 2;
      float4 qv = *(const float4*)&Q[(hb + q0 + q) * 64 + d4];
      Qst[d4][q] = qv.x; Qst[d4 + 1][q] = qv.y;
      Qst[d4 + 2][q] = qv.z; Qst[d4 + 3][q] = qv.w;
    }
    if (t < 64) qm[t] = maskf[bb * 1024 + q0 + t];
    __syncthreads();
    const float qmr[2] = {qm[2 * q2], qm[2 * q2 + 1]};
    for (int kt = 0; kt < nt; kt++) {
      const int k0 = kt * 64;
      __syncthreads();
#pragma unroll
      for (int i = 0; i < 4; i++) {
        int id = t + i * 256;
        int n = id >> 4, d4 = (id & 15) << 2;
        float4 kv = *(const float4*)&K[(hb + k0 + n) * 64 + d4];
        Kst[d4][n] = kv.x; Kst[d4 + 1][n] = kv.y;
        Kst[d4 + 2][n] = kv.z; Kst[d4 + 3][n] = kv.w;
        float4 vvv = *(const float4*)&V[(hb + k0 + n) * 64 + d4];
        *(float4*)&Vs[n][d4] = vvv;
      }
      if (t < 64) km[t] = maskf[bb * 1024 + k0 + t];
      __syncthreads();
      float kmr[8];
#pragma unroll
      for (int kk = 0; kk < 8; kk++) kmr[kk] = km[8 * j8 + kk];
      float s[2][8] = {};
      for (int d = 0; d < 64; d++) {
        float2 qv = *(const float2*)&Qst[d][2 * q2];
        float4 ka = *(const float4*)&Kst[d][8 * j8];
        float4 kb = *(const float4*)&Kst[d][8 * j8 + 4];
        s[0][0] = fmaf(qv.x, ka.x, s[0][0]); s[0][1] = fmaf(qv.x, ka.y, s[0][1]);
        s[0][2] = fmaf(qv.x, ka.z, s[0][2]); s[0][3] = fmaf(qv.x, ka.w, s[0][3]);
        s[0][4] = fmaf(qv.x, kb.x, s[0][4]); s[0][5] = fmaf(qv.x, kb.y, s[0][5]);
        s[0][6] = fmaf(qv.x, kb.z, s[0][6]); s[0][7] = fmaf(qv.x, kb.w, s[0][7]);
        s[1][0] = fmaf(qv.y, ka.x, s[1][0]); s[1][1] = fmaf(qv.y, ka.y, s[1][1]);
        s[1][2] = fmaf(qv.y, ka.z, s[1][2]); s[1][3] = fmaf(qv.y, ka.w, s[1][3]);
        s[1][4] = fmaf(qv.y, kb.x, s[1][4]); s[1][5] = fmaf(qv.y, kb.y, s[1][5]);
        s[1][6] = fmaf(qv.y, kb.z, s[1][6]); s[1][7] = fmaf(qv.y, kb.w, s[1][7]);
      }
#pragma unroll
      for (int qq = 0; qq < 2; qq++) {
        float rm = -INFINITY;
#pragma unroll
        for (int kk = 0; kk < 8; kk++) {
          float val = (qmr[qq] * kmr[kk] == 0.f) ? -1e9f : s[qq][kk] * 0.125f;
          s[qq][kk] = val;
          rm = fmaxf(rm, val);
        }
        rm = fmaxf(rm, __shfl_xor(rm, 1));
        rm = fmaxf(rm, __shfl_xor(rm, 2));
        rm = fmaxf(rm, __shfl_xor(rm, 4));
        float nm = fmaxf(mi[qq], rm);
        float al = __expf(mi[qq] - nm);
        mi[qq] = nm;
        float sum = 0.f;
#pragma unroll
        for (int kk = 0; kk < 8; kk++) {
          float p = __expf(s[qq][kk] - nm);
          Pst[8 * j8 + kk][2 * q2 + qq] = p;
          sum += p;
        }
        sum += __shfl_xor(sum, 1);
        sum += __shfl_xor(sum, 2);
        sum += __shfl_xor(sum, 4);
        li[qq] = li[qq] * al + sum;
#pragma unroll
        for (int dd = 0; dd < 8; dd++) o[qq][dd] *= al;
      }
      __syncthreads();
      for (int m = 0; m < 64; m++) {
        float2 pv = *(const float2*)&Pst[m][2 * q2];
        float4 va = *(const float4*)&Vs[m][8 * j8];
        float4 vb = *(const float4*)&Vs[m][8 * j8 + 4];
        o[0][0] = fmaf(pv.x, va.x, o[0][0]); o[0][1] = fmaf(pv.x, va.y, o[0][1]);
        o[0][2] = fmaf(pv.x, va.z, o[0][2]); o[0][3] = fmaf(pv.x, va.w, o[0][3]);
        o[0][4] = fmaf(pv.x, vb.x, o[0][4]); o[0][5] = fmaf(pv.x, vb.y, o[0][5]);
        o[0][6] = fmaf(pv.x, vb.z, o[0][6]); o[0][7] = fmaf(pv.x, vb.w, o[0][7]);
        o[1][0] = fmaf(pv.y, va.x, o[1][0]); o[1][1] = fmaf(pv.y, va.y, o[1][1]);
        o[1][2] = fmaf(pv.y, va.z, o[1][2]); o[1][3] = fmaf(pv.y, va.w, o[1][3]);
        o[1][4] = fmaf(pv.y, vb.x, o[1][4]); o[1][5] = fmaf(pv.y, vb.y, o[1][5]);
        o[1][6] = fmaf(pv.y, vb.z, o[1][6]); o[1][7] = fmaf(pv.y, vb.w, o[1][7]);
      }
    }
  }
#pragma unroll
  for (int qq = 0; qq < 2; qq++) {
    const int q = q0 + 2 * q2 + qq;
    const long long orow = ((long long)bb * 1024 + q) * 256;
    if (q < nv) {
      const float inv = 1.f / li[qq];
#pragma unroll
      for (int dd = 0; dd < 8; dd++)
        Out[orow + (long long)(8 * j8 + dd) * 4 + h] = o[qq][dd] * inv;
    } else {
#pragma unroll
      for (int dd = 0; dd < 8; dd++)
        Out[orow + (long long)(8 * j8 + dd) * 4 + h] =
            meanV[((bb * 4 + h) << 6) + 8 * j8 + dd];
    }
  }
}

// ------------------------------------------------------------- border (col 1024)
__global__ void k_border(float* __restrict__ C, const void* __restrict__ alpha,
                         const int* __restrict__ flagp) {
  const int f = *flagp;
  int g = blockIdx.x * 256 + threadIdx.x;
  if (g >= 4096) return;
  float a = ldin(alpha, 0, f);
  int bb = g >> 10, r = g & 1023;
  C[(long long)bb * 1050625 + (long long)r * 1025 + 1024] = a;
}

// -------------------------------------------------------------- Sinkhorn
// 4 groups x 32 blocks x 512 thr; each block owns 32 rows of C, held in LDS
// (131 KB) for all 200 sweeps. Row 1024 (alpha row) analytic. Flat 32-RMW
// barrier per half; u/v exchanged via L3 (agent-scope atomics).
__global__ __launch_bounds__(512) void k_sinkhorn(
    const float* __restrict__ C, const void* __restrict__ alphap,
    float* u, float* v, unsigned* ctr, void* __restrict__ outv,
    const int* __restrict__ flagp) {
  extern __shared__ float lds[];
  float* Cs = lds;            // [32*1025]
  float* sv = lds + 32800;    // [1025]
  float* su = sv + 1025;      // [1025]
  const int f = *flagp;
  const int bb = blockIdx.x >> 5;
  const int blk = blockIdx.x & 31;
  const int t = threadIdx.x;
  const int wid = t >> 6, lane = t & 63;
  const int r0 = blk << 5;  // rows [r0, r0+32)
  const float alpha = ldin(alphap, 0, f);
  const float* Cb = C + (long long)bb * 1050625;
  float* ub = u + bb * 1025;
  float* vb = v + bb * 1025;
  unsigned* cg = ctr + bb * 200;
  const float NORM = -7.624619086159398f;  // -log(2048)
  const float BIN = -0.6931471805599453f;  // log(1024)-log(2048)
  for (int i = t; i < 32 * 1025; i += 512) {
    int r = i / 1025, cc = i - r * 1025;
    Cs[i] = Cb[(long long)(r0 + r) * 1025 + cc];
  }
  for (int half = 0; half < 200; half++) {
    float* src = (half & 1) ? ub : vb;
    float* dst = (half & 1) ? vb : ub;
    for (int i = t; i < 1025; i += 512)
      sv[i] = __hip_atomic_load(src + i, __ATOMIC_RELAXED, __HIP_MEMORY_SCOPE_AGENT);
    __syncthreads();
    float svr[17];
#pragma unroll
    for (int i = 0; i < 17; i++) {
      int col = (i << 6) + lane;
      svr[i] = (col <= 1024) ? sv[col] : -INFINITY;
    }
#pragma unroll
    for (int j = 0; j < 4; j++) {
      const int rloc = (wid << 2) + j;
      const int n = r0 + rloc;
      const float* crow = Cs + rloc * 1025;
      float mx = -INFINITY;
      float vals[17];
#pragma unroll
      for (int i = 0; i < 17; i++) {
        int col = (i << 6) + lane;
        int cc = (col <= 1024) ? col : 0;
        float x = crow[cc] + svr[i];  // svr=-inf masks invalid lanes
        vals[i] = x;
        mx = fmaxf(mx, x);
      }
#pragma unroll
      for (int off = 32; off; off >>= 1) mx = fmaxf(mx, __shfl_xor(mx, off, 64));
      float s = 0.f;
#pragma unroll
      for (int i = 0; i < 17; i++) s += __expf(vals[i] - mx);
#pragma unroll
      for (int off = 32; off; off >>= 1) s += __shfl_xor(s, off, 64);
      if (lane == 0)
        __hip_atomic_store(dst + n, NORM - (mx + __logf(s)), __ATOMIC_RELAXED,
                           __HIP_MEMORY_SCOPE_AGENT);
    }
    if (blk == 0 && wid == 0) {  // alpha row: LSE = alpha + LSE(src)
      float mx = -INFINITY;
#pragma unroll
      for (int i = 0; i < 17; i++) mx = fmaxf(mx, svr[i]);
#pragma unroll
      for (int off = 32; off; off >>= 1) mx = fmaxf(mx, __shfl_xor(mx, off, 64));
      float s = 0.f;
#pragma unroll
      for (int i = 0; i < 17; i++) s += __expf(svr[i] - mx);
#pragma unroll
      for (int off = 32; off; off >>= 1) s += __shfl_xor(s, off, 64);
      if (lane == 0)
        __hip_atomic_store(dst + 1024, BIN - (alpha + mx + __logf(s)),
                           __ATOMIC_RELAXED, __HIP_MEMORY_SCOPE_AGENT);
    }
    __syncthreads();  // all dst stores issued (vmcnt drained at barrier)
    if (t == 0) {
      __hip_atomic_fetch_add(cg + half, 1u, __ATOMIC_RELEASE,
                             __HIP_MEMORY_SCOPE_AGENT);
      while (__hip_atomic_load(cg + half, __ATOMIC_RELAXED,
                               __HIP_MEMORY_SCOPE_AGENT) < 32u)
        __builtin_amdgcn_s_sleep(1);
    }
    __syncthreads();
  }
  for (int i = t; i < 1025; i += 512) {
    su[i] = __hip_atomic_load(ub + i, __ATOMIC_RELAXED, __HIP_MEMORY_SCOPE_AGENT);
    sv[i] = __hip_atomic_load(vb + i, __ATOMIC_RELAXED, __HIP_MEMORY_SCOPE_AGENT);
  }
  __syncthreads();
  const long long base = (long long)bb * 1050625;
  for (int i = t; i < 32 * 1025; i += 512) {
    int r = i / 1025, cc = i - r * 1025;
    float val = Cs[i] + su[r0 + r] + sv[cc] - NORM;
    if (f) ((float*)outv)[base + (long long)(r0 + r) * 1025 + cc] = val;
    else ((bf16*)outv)[base + (long long)(r0 + r) * 1025 + cc] = __float2bfloat16(val);
  }
  if (blk == 0) {
    const float un = su[1024];
    for (int cc = t; cc < 1025; cc += 512) {
      float val = alpha + un + sv[cc] - NORM;
      if (f) ((float*)outv)[base + (long long)1024 * 1025 + cc] = val;
      else ((bf16*)outv)[base + (long long)1024 * 1025 + cc] = __float2bfloat16(val);
    }
  }
}

// ================================================================== launch
extern "C" void kernel_launch(void* const* d_in, const int* in_sizes, int n_in,
                              void* d_out, int out_size, void* d_ws, size_t ws_size,
                              hipStream_t stream) {
  const void* scores = d_in[0];
  const void* distance = d_in[1];
  const void* enc_W0 = d_in[2];
  const void* enc_b0 = d_in[3];
  const void* enc_bn = d_in[4];
  const void* enc_W1 = d_in[5];
  const void* enc_b1 = d_in[6];
  const void* gnn_Wqkv = d_in[7];
  const void* gnn_bqkv = d_in[8];
  const void* gnn_Wm = d_in[9];
  const void* gnn_bm = d_in[10];
  const void* gnn_W1 = d_in[11];
  const void* gnn_b1 = d_in[12];
  const void* gnn_bn = d_in[13];
  const void* gnn_W2 = d_in[14];
  const void* gnn_b2 = d_in[15];
  const void* final_W = d_in[16];
  const void* final_b = d_in[17];
  const void* alpha = d_in[18];
  (void)in_sizes; (void)n_in; (void)out_size; (void)ws_size;

  char* ws = (char*)d_ws;
  size_t off = 0;
  auto alloc = [&](size_t bytes) -> void* {
    void* p = ws + off;
    off += (bytes + 255) & ~(size_t)255;
    return p;
  };
  int* flag = (int*)alloc(256);
  int* nvA = (int*)alloc(256);
  float* sn = (float*)alloc(20000 * 4);
  int* idxO = (int*)alloc(4096 * 4);
  float* valsO = (float*)alloc(4096 * 4);
  float* maskO = (float*)alloc(4096 * 4);
  float* emb = (float*)alloc((size_t)4096 * 256 * 4);
  float* Wp = (float*)alloc((size_t)65536 * 4);
  float* T0 = (float*)alloc((size_t)4096 * 256 * 4);
  float* X = (float*)alloc((size_t)4096 * 256 * 4);
  float* QKVh = (float*)alloc((size_t)3 * 4194304 * 4);
  float* meanV = (float*)alloc(16 * 64 * 4);
  float* msgb = (float*)alloc((size_t)4096 * 256 * 4);
  float* M2 = (float*)alloc((size_t)4096 * 256 * 4);
  float* Y1 = (float*)alloc((size_t)4096 * 512 * 4);
  float* MD = (float*)alloc((size_t)4096 * 256 * 4);
  float* Cpl = (float*)alloc((size_t)4 * 1050625 * 4);
  float* u = (float*)alloc(4100 * 4);
  float* v = (float*)alloc(4100 * 4);
  unsigned* ctr = (unsigned*)alloc(800 * 4);

  hipMemsetAsync(u, 0, 4100 * 4, stream);
  hipMemsetAsync(v, 0, 4100 * 4, stream);
  hipMemsetAsync(ctr, 0, 800 * 4, stream);

  static bool attrSet = false;
  if (!attrSet) {
    hipFuncSetAttribute(reinterpret_cast<const void*>(&k_sinkhorn),
                        hipFuncAttributeMaxDynamicSharedMemorySize, 139400);
    attrSet = true;
  }

  const dim3 b256(256);
  k_detect<<<1, b256, 0, stream>>>(distance, flag);
  k_nms<<<4, 512, 0, stream>>>(scores, flag, sn);
  k_sort<<<4, 1024, 0, stream>>>(sn, idxO, valsO, maskO, nvA);
  k_emb<<<4096, b256, 0, stream>>>(idxO, valsO, distance, emb, flag);
  k_padw0<<<256, b256, 0, stream>>>(enc_W0, Wp, flag);

  gemm_nt<1, false, 1, 64><<<dim3(4, 64, 1), b256, 0, stream>>>(
      emb, nullptr, 256, Wp, enc_b0, enc_bn, T0, 256, 256, 256, 1.f,
      0, 0, 0, 0, 0, 0, flag);
  gemm_nt<0, false, 0, 64><<<dim3(4, 64, 1), b256, 0, stream>>>(
      T0, nullptr, 256, enc_W1, enc_b1, nullptr, X, 256, 256, 256, 1.f,
      0, 0, 0, 0, 0, 0, flag);

  for (int l = 0; l < 4; l++) {
    gemm_nt<3, false, 0, 128><<<dim3(12, 32, 1), b256, 0, stream>>>(
        X, nullptr, 256, gnn_Wqkv, gnn_bqkv, nullptr, QKVh, 0, 768, 256, 1.f,
        0, 0, 0, (long long)l * 196608, (long long)l * 768, 0, flag);
    k_meanv<<<16, b256, 0, stream>>>(QKVh, meanV);
    k_attn<<<dim3(16, 4, 4), b256, 0, stream>>>(QKVh, maskO, nvA, meanV, msgb);
    gemm_nt<0, false, 0, 64><<<dim3(4, 64, 1), b256, 0, stream>>>(
        msgb, nullptr, 256, gnn_Wm, gnn_bm, nullptr, M2, 256, 256, 256, 1.f,
        0, 0, 0, (long long)l * 65536, (long long)l * 256, 0, flag);
    gemm_nt<1, true, 0, 128><<<dim3(8, 32, 1), b256, 0, stream>>>(
        X, M2, 256, gnn_W1, gnn_b1, gnn_bn, Y1, 512, 512, 512, 1.f,
        0, 0, 0, (long long)l * 262144, (long long)l * 512, (long long)l * 2048, flag);
    gemm_nt<2, false, 0, 64><<<dim3(4, 64, 1), b256, 0, stream>>>(
        Y1, nullptr, 512, gnn_W2, gnn_b2, nullptr, X, 256, 256, 512, 1.f,
        0, 0, 0, (long long)l * 131072, (long long)l * 256, 0, flag);
  }
  gemm_nt<0, false, 0, 64><<<dim3(4, 64, 1), b256, 0, stream>>>(
      X, nullptr, 256, final_W, final_b, nullptr, MD, 256, 256, 256, 1.f,
      0, 0, 0, 0, 0, 0, flag);
  gemm_nt<4, false, 1, 128><<<dim3(16, 8, 4), b256, 0, stream>>>(
      MD, nullptr, 256, MD, nullptr, nullptr, Cpl, 1025, 1024, 256, 0.0625f,
      262144, 262144, 1050625, 0, 0, 0, flag);
  k_border<<<16, b256, 0, stream>>>(Cpl, alpha, flag);
  k_sinkhorn<<<128, 512, 139400, stream>>>(Cpl, alpha, u, v, ctr, d_out, flag);
}

// Round 6
// 2098.264 us; speedup vs baseline: 3.2049x; 1.1572x over previous
//
#include <hip/hip_runtime.h>
#include <hip/hip_bf16.h>

typedef __hip_bfloat16 bf16;
typedef __attribute__((ext_vector_type(8))) short short8;
typedef __attribute__((ext_vector_type(4))) float f32x4;
#define DEV __device__ __forceinline__

// Adaptive input load: flag==1 -> fp32 data, flag==0 -> bf16 data.
DEV float ldin(const void* p, long long i, int f) {
  return f ? ((const float*)p)[i]
           : __uint_as_float(((unsigned)((const unsigned short*)p)[i]) << 16);
}
DEV unsigned short f2bf(float x) {  // RNE f32->bf16
  unsigned u = __float_as_uint(x);
  return (unsigned short)((u + 0x7FFFu + ((u >> 16) & 1u)) >> 16);
}
DEV float bf2f(unsigned short h) { return __uint_as_float((unsigned)h << 16); }

// ------------------------------------------------------------ dtype detector
__global__ void k_detect(const void* __restrict__ dist, int* __restrict__ flag) {
  const unsigned short* p = (const unsigned short*)dist;
  __shared__ int bad;
  if (threadIdx.x == 0) bad = 0;
  __syncthreads();
  int cnt = 0;
  for (int i = threadIdx.x; i < 65536; i += 256) {
    unsigned e = (p[i] >> 7) & 0xFF;
    if (e >= 0x86) cnt++;
  }
  atomicAdd(&bad, cnt);
  __syncthreads();
  if (threadIdx.x == 0) *flag = (bad > 100) ? 1 : 0;
}

// ------------------------------------------------- fused NMS (one block/batch)
DEV void mp5_sep(const float* in, float* tmp, float* out, int t) {
  for (int i = t; i < 5000; i += 512) {
    int y = i / 100, x = i % 100;
    int x0 = x - 2 < 0 ? 0 : x - 2, x1 = x + 2 > 99 ? 99 : x + 2;
    float m = -INFINITY;
    for (int xx = x0; xx <= x1; xx++) m = fmaxf(m, in[y * 100 + xx]);
    tmp[i] = m;
  }
  __syncthreads();
  for (int i = t; i < 5000; i += 512) {
    int y = i / 100, x = i % 100;
    int y0 = y - 2 < 0 ? 0 : y - 2, y1 = y + 2 > 49 ? 49 : y + 2;
    float m = -INFINITY;
    for (int yy = y0; yy <= y1; yy++) m = fmaxf(m, tmp[yy * 100 + x]);
    out[i] = m;
  }
  __syncthreads();
}

__global__ __launch_bounds__(512) void k_nms(const void* __restrict__ scores,
                                             const int* __restrict__ flagp,
                                             float* __restrict__ sn) {
  const int f = *flagp;
  const int bb = blockIdx.x, t = threadIdx.x;
  __shared__ float S[5000], T[5000], P[5000], MK[5000], SP[5000], SS[5000];
  for (int i = t; i < 5000; i += 512) S[i] = ldin(scores, bb * 5000 + i, f);
  __syncthreads();
  mp5_sep(S, T, P, t);
  for (int i = t; i < 5000; i += 512) MK[i] = (S[i] == P[i]) ? 1.f : 0.f;
  __syncthreads();
  for (int r = 0; r < 2; r++) {
    mp5_sep(MK, T, P, t);
    for (int i = t; i < 5000; i += 512) {
      SP[i] = (P[i] > 0.f) ? 1.f : 0.f;
      SS[i] = (SP[i] != 0.f) ? 0.f : S[i];
    }
    __syncthreads();
    mp5_sep(SS, T, P, t);
    for (int i = t; i < 5000; i += 512)
      if (MK[i] == 0.f) MK[i] = ((SS[i] == P[i]) && (SP[i] == 0.f)) ? 1.f : 0.f;
    __syncthreads();
  }
  for (int i = t; i < 5000; i += 512)
    sn[bb * 5000 + i] = (MK[i] != 0.f) ? S[i] : 0.f;
}

// ------------------------------------------------ exact top-k via bitonic sort
__global__ __launch_bounds__(1024) void k_sort(
    const float* __restrict__ sn,
    int* __restrict__ idxO, float* __restrict__ valsO, float* __restrict__ maskO,
    int* __restrict__ nvp) {
  __shared__ unsigned long long keys[8192];
  __shared__ int cnt;
  const int bb = blockIdx.x;
  const int t = threadIdx.x;
  if (t == 0) cnt = 0;
  for (int i = t; i < 8192; i += 1024) {
    unsigned long long kk;
    if (i < 5000) {
      float v = sn[bb * 5000 + i];
      unsigned vb = __float_as_uint(v);  // scores >= 0 -> monotone bits
      kk = ((unsigned long long)vb << 32) | (unsigned)(0xFFFFFFFFu - (unsigned)i);
    } else {
      kk = 0ull;
    }
    keys[i] = ~kk;
  }
  __syncthreads();
  for (int k = 2; k <= 8192; k <<= 1) {
    for (int j = k >> 1; j > 0; j >>= 1) {
      for (int i = t; i < 8192; i += 1024) {
        int ixj = i ^ j;
        if (ixj > i) {
          unsigned long long a = keys[i], b = keys[ixj];
          bool up = ((i & k) == 0);
          if (up ? (a > b) : (a < b)) { keys[i] = b; keys[ixj] = a; }
        }
      }
      __syncthreads();
    }
  }
  {
    unsigned long long kk = ~keys[t];
    unsigned idx = 0xFFFFFFFFu - (unsigned)(kk & 0xFFFFFFFFu);
    float v = __uint_as_float((unsigned)(kk >> 32));
    idxO[bb * 1024 + t] = (int)idx;
    valsO[bb * 1024 + t] = v;
    bool valid = (v > 0.015f);
    maskO[bb * 1024 + t] = valid ? 1.f : 0.f;
    unsigned long long bal = __ballot(valid);
    if ((t & 63) == 0) atomicAdd(&cnt, (int)__popcll(bal));
  }
  __syncthreads();
  if (t == 0) nvp[bb] = cnt;
}

// --------------------------------------------------------- embedding build
__global__ void k_emb(const int* __restrict__ idxO, const float* __restrict__ valsO,
                      const void* __restrict__ distance, float* __restrict__ emb,
                      const int* __restrict__ flagp) {
  const int f = *flagp;
  const int vtx = blockIdx.x;
  const int bb = vtx >> 10, i = vtx & 1023;
  const int t = threadIdx.x;
  const int id = idxO[bb * 1024 + i];
  const int cy = id / 100, cx = id % 100;
  const float nvx = ((float)cx - 50.0f + 0.5f) / 100.0f;
  const float nvy = ((float)cy - 25.0f + 0.5f) / 50.0f;
  float* e = emb + (long long)vtx * 256;
  for (int c = t; c < 256; c += 256) {
    float val;
    if (c == 0) val = nvx;
    else if (c == 1) val = nvy;
    else if (c < 42) {
      int d = c - 2, fq = d >> 2, r = d & 3;
      float freq = (float)(1 << fq);
      float ang = ((r == 0 || r == 2) ? nvx : nvy) * freq;
      val = (r < 2) ? sinf(ang) : cosf(ang);
    } else if (c == 42) {
      val = valsO[bb * 1024 + i];
    } else if (c < 235) {
      int d = c - 43, cls = d >> 6, ii = (d >> 3) & 7, jj = d & 7;
      val = ldin(distance,
                 (((long long)bb * 3 + cls) * 400 + (cy * 8 + ii)) * 800 + (cx * 8 + jj), f);
    } else {
      val = 0.f;
    }
    e[c] = val;
  }
}

// --------------------------------------------- pad enc_W0 [256][235]->[256][256]
__global__ void k_padw0(const void* __restrict__ W0, float* __restrict__ Wp,
                        const int* __restrict__ flagp) {
  const int f = *flagp;
  int i = blockIdx.x * 256 + threadIdx.x;
  int r = i >> 8, c = i & 255;
  Wp[i] = (c < 235) ? ldin(W0, (long long)r * 235 + c, f) : 0.f;
}

// ------------------------------------------------------- MFMA GEMM (NT, bf16x3)
// out[m,n] = sum_k A[m,k]*W[n,k]. A fp32 split hi/lo bf16; W split if fp32,
// raw bf16 otherwise (Bl=0 -> 2 mfma). 64x64 tile, BK=32, 256 thr, 4 waves.
// MODE: 0 +bias; 1 +bias,BN,ReLU; 2 +bias+resid(in-place Cout); 3 QKV-permute;
// 4 *scale. WF=1: W fp32 workspace; WF=0: W dtype per runtime flag.
template <int MODE, bool SPLIT, int WF>
__global__ __launch_bounds__(256) void gemm_mf(
    const float* __restrict__ A, const float* __restrict__ A2, int lda,
    const void* __restrict__ W, const void* __restrict__ bias,
    const void* __restrict__ bn, float* __restrict__ Cout, int ldc,
    int N, int K, float scale,
    long long aBatch, long long wBatch, long long cBatch,
    long long wOff, long long bOff, long long bnOff,
    const int* __restrict__ flagp) {
  const int rf = *flagp;
  const bool wsplit = WF ? true : (rf != 0);  // fp32 W -> need lo term
  A += (long long)blockIdx.z * aBatch;
  Cout += (long long)blockIdx.z * cBatch;
  const long long wbase = wOff + (long long)blockIdx.z * wBatch;
  __shared__ unsigned short Ah[2048], Al[2048], Bh[2048], Bl[2048];
  const int t = threadIdx.x;
  const int m0 = blockIdx.y * 64, n0 = blockIdx.x * 64;
  const int w = t >> 6, lane = t & 63;
  const int quad = lane >> 4, l15 = lane & 15;
  ushort4 rah[2], ral[2], rbh[2], rbl[2];
  auto loadT = [&](int k0) {
#pragma unroll
    for (int i = 0; i < 2; i++) {
      int id = t + (i << 8);
      int m = id >> 3, k4 = (id & 7) << 2;
      const float* Ap = A;
      int kc = k0 + k4;
      if (SPLIT && kc >= 256) { Ap = A2; kc -= 256; }
      float4 a = *(const float4*)&Ap[(long long)(m0 + m) * lda + kc];
      ushort4 h, l;
      h.x = f2bf(a.x); l.x = f2bf(a.x - bf2f(h.x));
      h.y = f2bf(a.y); l.y = f2bf(a.y - bf2f(h.y));
      h.z = f2bf(a.z); l.z = f2bf(a.z - bf2f(h.z));
      h.w = f2bf(a.w); l.w = f2bf(a.w - bf2f(h.w));
      rah[i] = h; ral[i] = l;
      long long widx = wbase + (long long)(n0 + m) * K + k0 + k4;
      if (wsplit) {
        float4 b = *(const float4*)((const float*)W + widx);
        ushort4 bh_, bl_;
        bh_.x = f2bf(b.x); bl_.x = f2bf(b.x - bf2f(bh_.x));
        bh_.y = f2bf(b.y); bl_.y = f2bf(b.y - bf2f(bh_.y));
        bh_.z = f2bf(b.z); bl_.z = f2bf(b.z - bf2f(bh_.z));
        bh_.w = f2bf(b.w); bl_.w = f2bf(b.w - bf2f(bh_.w));
        rbh[i] = bh_; rbl[i] = bl_;
      } else {
        rbh[i] = *(const ushort4*)((const unsigned short*)W + widx);
      }
    }
  };
  auto storeT = [&]() {
#pragma unroll
    for (int i = 0; i < 2; i++) {
      int id = t + (i << 8);
      int m = id >> 3, k4 = (id & 7) << 2;
      int q = k4 >> 3, j0 = k4 & 7;
      int lidx = (q * 64 + m) * 8 + j0;
      *(ushort4*)&Ah[lidx] = rah[i];
      *(ushort4*)&Al[lidx] = ral[i];
      *(ushort4*)&Bh[lidx] = rbh[i];
      if (wsplit) *(ushort4*)&Bl[lidx] = rbl[i];
    }
  };
  f32x4 acc[4];
#pragma unroll
  for (int c = 0; c < 4; c++) acc[c] = (f32x4){0.f, 0.f, 0.f, 0.f};
  loadT(0);
  const int mr = w * 16 + l15;
  for (int k0 = 0; k0 < K; k0 += 32) {
    storeT();
    __syncthreads();
    if (k0 + 32 < K) loadT(k0 + 32);
    short8 fa = *(const short8*)&Ah[(quad * 64 + mr) * 8];
    short8 fal = *(const short8*)&Al[(quad * 64 + mr) * 8];
#pragma unroll
    for (int cb = 0; cb < 4; cb++) {
      int nr = cb * 16 + l15;
      short8 fb = *(const short8*)&Bh[(quad * 64 + nr) * 8];
      acc[cb] = __builtin_amdgcn_mfma_f32_16x16x32_bf16(fa, fb, acc[cb], 0, 0, 0);
      acc[cb] = __builtin_amdgcn_mfma_f32_16x16x32_bf16(fal, fb, acc[cb], 0, 0, 0);
      if (wsplit) {
        short8 fbl = *(const short8*)&Bl[(quad * 64 + nr) * 8];
        acc[cb] = __builtin_amdgcn_mfma_f32_16x16x32_bf16(fa, fbl, acc[cb], 0, 0, 0);
      }
    }
    __syncthreads();
  }
#pragma unroll
  for (int cb = 0; cb < 4; cb++) {
    const int n = n0 + cb * 16 + l15;
    float bv = 0.f, g = 0.f, bt = 0.f, mu = 0.f, vr = 0.f;
    if (MODE != 4) bv = ldin(bias, bOff + n, rf);
    if (MODE == 1) {
      g = ldin(bn, bnOff + n, rf);
      bt = ldin(bn, bnOff + N + n, rf);
      mu = ldin(bn, bnOff + 2 * N + n, rf);
      vr = ldin(bn, bnOff + 3 * N + n, rf);
    }
#pragma unroll
    for (int r = 0; r < 4; r++) {
      const int m = m0 + w * 16 + quad * 4 + r;
      float v = acc[cb][r];
      if (MODE == 4) v *= scale;
      else v += bv;
      if (MODE == 1) {
        v = g * (v - mu) / sqrtf(vr + 1e-5f) + bt;
        v = fmaxf(v, 0.f);
      }
      if (MODE == 2) v += Cout[(long long)m * ldc + n];
      if (MODE == 3) {
        int qkv = n >> 8, c = n & 255, h = c & 3, d = c >> 2;
        int bb2 = m >> 10, nn = m & 1023;
        Cout[(long long)qkv * 4194304 +
             (((long long)(bb2 * 4 + h)) * 1024 + nn) * 64 + d] = v;
      } else {
        Cout[(long long)m * ldc + n] = v;
      }
    }
  }
}

// ------------------------------------------------ per-(b,h) mean of V rows
__global__ __launch_bounds__(256) void k_meanv(const float* __restrict__ QKV,
                                               float* __restrict__ meanV) {
  const int bh = blockIdx.x;  // 0..15
  const int t = threadIdx.x;
  const int c4 = t >> 6, d = t & 63;
  __shared__ float part[4][64];
  const float* V = QKV + 8388608 + (long long)bh * 65536;
  float s = 0.f;
  for (int r = c4 * 256; r < (c4 + 1) * 256; r++) s += V[r * 64 + d];
  part[c4][d] = s;
  __syncthreads();
  if (c4 == 0)
    meanV[bh * 64 + d] =
        (part[0][d] + part[1][d] + part[2][d] + part[3][d]) * (1.f / 1024.f);
}

// -------------------------------------------------- flash-style attention
__global__ __launch_bounds__(256) void k_attn(
    const float* __restrict__ QKV, const float* __restrict__ maskf,
    const int* __restrict__ nvp, const float* __restrict__ meanV,
    float* __restrict__ Out) {
  const int qt = blockIdx.x, h = blockIdx.y, bb = blockIdx.z;
  const int t = threadIdx.x;
  const int q2 = t >> 3, j8 = t & 7;
  __shared__ float Qst[64][68];
  __shared__ float Kst[64][68];
  __shared__ float Vs[64][72];
  __shared__ float Pst[64][68];
  __shared__ float qm[64], km[64];
  const float* Q = QKV;
  const float* K = QKV + 4194304;
  const float* V = QKV + 8388608;
  const long long hb = ((long long)bb * 4 + h) * 1024;
  const int q0 = qt * 64;
  const int nv = nvp[bb];
  const int nt = (nv + 63) >> 6;
  float mi[2] = {-INFINITY, -INFINITY};
  float li[2] = {0.f, 0.f};
  float o[2][8] = {};
  if (q0 < nv) {
#pragma unroll
    for (int i = 0; i < 4; i++) {
      int id = t + i * 256;
      int q = id >> 4, d4 = (id & 15) << 2;
      float4 qv = *(const float4*)&Q[(hb + q0 + q) * 64 + d4];
      Qst[d4][q] = qv.x; Qst[d4 + 1][q] = qv.y;
      Qst[d4 + 2][q] = qv.z; Qst[d4 + 3][q] = qv.w;
    }
    if (t < 64) qm[t] = maskf[bb * 1024 + q0 + t];
    __syncthreads();
    const float qmr[2] = {qm[2 * q2], qm[2 * q2 + 1]};
    for (int kt = 0; kt < nt; kt++) {
      const int k0 = kt * 64;
      __syncthreads();
#pragma unroll
      for (int i = 0; i < 4; i++) {
        int id = t + i * 256;
        int n = id >> 4, d4 = (id & 15) << 2;
        float4 kv = *(const float4*)&K[(hb + k0 + n) * 64 + d4];
        Kst[d4][n] = kv.x; Kst[d4 + 1][n] = kv.y;
        Kst[d4 + 2][n] = kv.z; Kst[d4 + 3][n] = kv.w;
        float4 vvv = *(const float4*)&V[(hb + k0 + n) * 64 + d4];
        *(float4*)&Vs[n][d4] = vvv;
      }
      if (t < 64) km[t] = maskf[bb * 1024 + k0 + t];
      __syncthreads();
      float kmr[8];
#pragma unroll
      for (int kk = 0; kk < 8; kk++) kmr[kk] = km[8 * j8 + kk];
      float s[2][8] = {};
      for (int d = 0; d < 64; d++) {
        float2 qv = *(const float2*)&Qst[d][2 * q2];
        float4 ka = *(const float4*)&Kst[d][8 * j8];
        float4 kb = *(const float4*)&Kst[d][8 * j8 + 4];
        s[0][0] = fmaf(qv.x, ka.x, s[0][0]); s[0][1] = fmaf(qv.x, ka.y, s[0][1]);
        s[0][2] = fmaf(qv.x, ka.z, s[0][2]); s[0][3] = fmaf(qv.x, ka.w, s[0][3]);
        s[0][4] = fmaf(qv.x, kb.x, s[0][4]); s[0][5] = fmaf(qv.x, kb.y, s[0][5]);
        s[0][6] = fmaf(qv.x, kb.z, s[0][6]); s[0][7] = fmaf(qv.x, kb.w, s[0][7]);
        s[1][0] = fmaf(qv.y, ka.x, s[1][0]); s[1][1] = fmaf(qv.y, ka.y, s[1][1]);
        s[1][2] = fmaf(qv.y, ka.z, s[1][2]); s[1][3] = fmaf(qv.y, ka.w, s[1][3]);
        s[1][4] = fmaf(qv.y, kb.x, s[1][4]); s[1][5] = fmaf(qv.y, kb.y, s[1][5]);
        s[1][6] = fmaf(qv.y, kb.z, s[1][6]); s[1][7] = fmaf(qv.y, kb.w, s[1][7]);
      }
#pragma unroll
      for (int qq = 0; qq < 2; qq++) {
        float rm = -INFINITY;
#pragma unroll
        for (int kk = 0; kk < 8; kk++) {
          float val = (qmr[qq] * kmr[kk] == 0.f) ? -1e9f : s[qq][kk] * 0.125f;
          s[qq][kk] = val;
          rm = fmaxf(rm, val);
        }
        rm = fmaxf(rm, __shfl_xor(rm, 1));
        rm = fmaxf(rm, __shfl_xor(rm, 2));
        rm = fmaxf(rm, __shfl_xor(rm, 4));
        float nm = fmaxf(mi[qq], rm);
        float al = __expf(mi[qq] - nm);
        mi[qq] = nm;
        float sum = 0.f;
#pragma unroll
        for (int kk = 0; kk < 8; kk++) {
          float p = __expf(s[qq][kk] - nm);
          Pst[8 * j8 + kk][2 * q2 + qq] = p;
          sum += p;
        }
        sum += __shfl_xor(sum, 1);
        sum += __shfl_xor(sum, 2);
        sum += __shfl_xor(sum, 4);
        li[qq] = li[qq] * al + sum;
#pragma unroll
        for (int dd = 0; dd < 8; dd++) o[qq][dd] *= al;
      }
      __syncthreads();
      for (int m = 0; m < 64; m++) {
        float2 pv = *(const float2*)&Pst[m][2 * q2];
        float4 va = *(const float4*)&Vs[m][8 * j8];
        float4 vb = *(const float4*)&Vs[m][8 * j8 + 4];
        o[0][0] = fmaf(pv.x, va.x, o[0][0]); o[0][1] = fmaf(pv.x, va.y, o[0][1]);
        o[0][2] = fmaf(pv.x, va.z, o[0][2]); o[0][3] = fmaf(pv.x, va.w, o[0][3]);
        o[0][4] = fmaf(pv.x, vb.x, o[0][4]); o[0][5] = fmaf(pv.x, vb.y, o[0][5]);
        o[0][6] = fmaf(pv.x, vb.z, o[0][6]); o[0][7] = fmaf(pv.x, vb.w, o[0][7]);
        o[1][0] = fmaf(pv.y, va.x, o[1][0]); o[1][1] = fmaf(pv.y, va.y, o[1][1]);
        o[1][2] = fmaf(pv.y, va.z, o[1][2]); o[1][3] = fmaf(pv.y, va.w, o[1][3]);
        o[1][4] = fmaf(pv.y, vb.x, o[1][4]); o[1][5] = fmaf(pv.y, vb.y, o[1][5]);
        o[1][6] = fmaf(pv.y, vb.z, o[1][6]); o[1][7] = fmaf(pv.y, vb.w, o[1][7]);
      }
    }
  }
#pragma unroll
  for (int qq = 0; qq < 2; qq++) {
    const int q = q0 + 2 * q2 + qq;
    const long long orow = ((long long)bb * 1024 + q) * 256;
    if (q < nv) {
      const float inv = 1.f / li[qq];
#pragma unroll
      for (int dd = 0; dd < 8; dd++)
        Out[orow + (long long)(8 * j8 + dd) * 4 + h] = o[qq][dd] * inv;
    } else {
#pragma unroll
      for (int dd = 0; dd < 8; dd++)
        Out[orow + (long long)(8 * j8 + dd) * 4 + h] =
            meanV[((bb * 4 + h) << 6) + 8 * j8 + dd];
    }
  }
}

// ------------------------------------------------------------- border (col 1024)
__global__ void k_border(float* __restrict__ C, const void* __restrict__ alpha,
                         const int* __restrict__ flagp) {
  const int f = *flagp;
  int g = blockIdx.x * 256 + threadIdx.x;
  if (g >= 4096) return;
  float a = ldin(alpha, 0, f);
  int bb = g >> 10, r = g & 1023;
  C[(long long)bb * 1050625 + (long long)r * 1025 + 1024] = a;
}

// -------------------------------------------------------------- Sinkhorn
// 4 groups x 32 blocks x 512 thr. Block holds 32 rows as exp(C-rowmax) in LDS;
// LSE(c+sv) = mc + ms + log(sum expC*exp(sv-ms)) -> pure fma dots per half.
// Barrier: per-block flag store (parity slots) + 32-lane gather poll; conv bit
// in flag gives consensus early-exit.
__global__ __launch_bounds__(512) void k_sinkhorn(
    const float* __restrict__ C, const void* __restrict__ alphap,
    float* u, float* v, unsigned* flags, void* __restrict__ outv,
    const int* __restrict__ flagp) {
  extern __shared__ float lds[];
  float* expC = lds;                  // 32*1025
  float* sv = lds + 32800;            // 1025
  float* su = sv + 1025;              // 1025
  float* mc = su + 1025;              // 32
  float* wredm = mc + 32;             // 8
  float* wredd = wredm + 8;           // 8
  int* qf = (int*)(wredd + 8);        // 1
  const int f = *flagp;
  const int bb = blockIdx.x >> 5;
  const int blk = blockIdx.x & 31;
  const int t = threadIdx.x;
  const int wid = t >> 6, lane = t & 63;
  const int r0g = blk << 5;
  const int rw = wid << 2;
  const float alpha = ldin(alphap, 0, f);
  const float* Cb = C + (long long)bb * 1050625;
  float* ub = u + bb * 1025;
  float* vb = v + bb * 1025;
  unsigned* fl = flags + bb * 64;
  const float NORM = -7.624619086159398f;  // -log(2048)
  const float BIN = -0.6931471805599453f;  // log(1024)-log(2048)
  for (int i = t; i < 32800; i += 512)
    expC[i] = Cb[(long long)r0g * 1025 + i];
  __syncthreads();
#pragma unroll
  for (int j = 0; j < 4; j++) {
    const float* cr = expC + (rw + j) * 1025;
    float mx = -INFINITY;
#pragma unroll
    for (int i = 0; i < 17; i++) {
      int col = (i << 6) + lane;
      if (col <= 1024) mx = fmaxf(mx, cr[col]);
    }
#pragma unroll
    for (int o = 32; o; o >>= 1) mx = fmaxf(mx, __shfl_xor(mx, o, 64));
    if (lane == 0) mc[rw + j] = mx;
  }
  __syncthreads();
  for (int i = t; i < 32800; i += 512) {
    int r = i / 1025;
    expC[i] = __expf(expC[i] - mc[r]);
  }
  __syncthreads();
  float prevU[4] = {0, 0, 0, 0}, prevV[4] = {0, 0, 0, 0};
  float prevAU = 0.f, prevAV = 0.f;
  for (int half = 0; half < 200; half++) {
    float* dst = (half & 1) ? vb : ub;
    const float* srcf = (half & 1) ? ub : vb;
    const unsigned long long* s64 = (const unsigned long long*)srcf;
    float lm;
    {
      unsigned long long d = __hip_atomic_load(s64 + t, __ATOMIC_RELAXED,
                                               __HIP_MEMORY_SCOPE_AGENT);
      float lo = __uint_as_float((unsigned)d);
      float hi = __uint_as_float((unsigned)(d >> 32));
      sv[2 * t] = lo;
      sv[2 * t + 1] = hi;
      lm = fmaxf(lo, hi);
      if (t == 0) {
        float e = __uint_as_float(__hip_atomic_load(
            (const unsigned*)(srcf + 1024), __ATOMIC_RELAXED, __HIP_MEMORY_SCOPE_AGENT));
        sv[1024] = e;
        lm = fmaxf(lm, e);
      }
    }
#pragma unroll
    for (int o = 32; o; o >>= 1) lm = fmaxf(lm, __shfl_xor(lm, o, 64));
    if (lane == 0) wredm[wid] = lm;
    __syncthreads();
    float ms = wredm[0];
#pragma unroll
    for (int k = 1; k < 8; k++) ms = fmaxf(ms, wredm[k]);
    float svr[17];
#pragma unroll
    for (int i = 0; i < 17; i++) {
      int col = (i << 6) + lane;
      svr[i] = (col <= 1024) ? __expf(sv[col] - ms) : 0.f;
    }
    float wd = 0.f;
    float* prev = (half & 1) ? prevV : prevU;
    float dsts[4];
#pragma unroll
    for (int j = 0; j < 4; j++) {
      const float* cr = expC + (rw + j) * 1025;
      float s = 0.f;
#pragma unroll
      for (int i = 0; i < 17; i++) {
        int col = (i << 6) + lane;
        int cc = (col <= 1024) ? col : 0;  // svr=0 masks tail
        s = fmaf(cr[cc], svr[i], s);
      }
#pragma unroll
      for (int o = 32; o; o >>= 1) s += __shfl_xor(s, o, 64);
      float nval = NORM - (mc[rw + j] + ms + __logf(s));
      dsts[j] = nval;
      wd = fmaxf(wd, fabsf(nval - prev[j]));
      prev[j] = nval;
    }
    if (lane == 0) {
      unsigned long long p0 = ((unsigned long long)__float_as_uint(dsts[1]) << 32) |
                              __float_as_uint(dsts[0]);
      unsigned long long p1 = ((unsigned long long)__float_as_uint(dsts[3]) << 32) |
                              __float_as_uint(dsts[2]);
      __hip_atomic_store((unsigned long long*)(dst + r0g + rw), p0,
                         __ATOMIC_RELAXED, __HIP_MEMORY_SCOPE_AGENT);
      __hip_atomic_store((unsigned long long*)(dst + r0g + rw + 2), p1,
                         __ATOMIC_RELAXED, __HIP_MEMORY_SCOPE_AGENT);
    }
    if (blk == 0 && wid == 0) {  // alpha row: LSE = alpha + ms + log(sum expsv)
      float s = 0.f;
#pragma unroll
      for (int i = 0; i < 17; i++) s += svr[i];
#pragma unroll
      for (int o = 32; o; o >>= 1) s += __shfl_xor(s, o, 64);
      float nval = BIN - (alpha + ms + __logf(s));
      float* pa = (half & 1) ? &prevAV : &prevAU;
      wd = fmaxf(wd, fabsf(nval - *pa));
      *pa = nval;
      if (lane == 0)
        __hip_atomic_store((unsigned*)(dst + 1024), __float_as_uint(nval),
                           __ATOMIC_RELAXED, __HIP_MEMORY_SCOPE_AGENT);
    }
    if (lane == 0) wredd[wid] = wd;
    __syncthreads();
    if (wid == 0) {
      if (lane == 0) {
        float bmax = wredd[0];
#pragma unroll
        for (int k = 1; k < 8; k++) bmax = fmaxf(bmax, wredd[k]);
        unsigned val = ((unsigned)(half + 1) << 1) | (bmax < 1e-4f ? 1u : 0u);
        __hip_atomic_store(fl + ((half & 1) << 5) + blk, val, __ATOMIC_RELEASE,
                           __HIP_MEMORY_SCOPE_AGENT);
      }
      int q = 0;
      if (lane < 32) {
        const unsigned tgt = (unsigned)(half + 1) << 1;
        unsigned vv;
        for (;;) {
          vv = __hip_atomic_load(fl + ((half & 1) << 5) + lane, __ATOMIC_ACQUIRE,
                                 __HIP_MEMORY_SCOPE_AGENT);
          if (vv >= tgt) break;
          __builtin_amdgcn_s_sleep(1);
        }
        unsigned long long cb_ = __ballot((vv & 1u) != 0u);
        q = (((unsigned)cb_) == 0xFFFFFFFFu && half >= 50 && (half & 1)) ? 1 : 0;
        if (lane == 0) *qf = q;
      }
    }
    __syncthreads();
    if (*qf) break;
  }
  {  // final u,v stage
    unsigned long long du = __hip_atomic_load(
        (const unsigned long long*)ub + t, __ATOMIC_RELAXED, __HIP_MEMORY_SCOPE_AGENT);
    unsigned long long dv = __hip_atomic_load(
        (const unsigned long long*)vb + t, __ATOMIC_RELAXED, __HIP_MEMORY_SCOPE_AGENT);
    su[2 * t] = __uint_as_float((unsigned)du);
    su[2 * t + 1] = __uint_as_float((unsigned)(du >> 32));
    sv[2 * t] = __uint_as_float((unsigned)dv);
    sv[2 * t + 1] = __uint_as_float((unsigned)(dv >> 32));
    if (t == 0) {
      su[1024] = __uint_as_float(__hip_atomic_load(
          (const unsigned*)(ub + 1024), __ATOMIC_RELAXED, __HIP_MEMORY_SCOPE_AGENT));
      sv[1024] = __uint_as_float(__hip_atomic_load(
          (const unsigned*)(vb + 1024), __ATOMIC_RELAXED, __HIP_MEMORY_SCOPE_AGENT));
    }
  }
  __syncthreads();
  const long long base = (long long)bb * 1050625;
  for (int i = t; i < 32800; i += 512) {
    int r = i / 1025, cc = i - r * 1025;
    float val = Cb[(long long)r0g * 1025 + i] + su[r0g + r] + sv[cc] - NORM;
    if (f) ((float*)outv)[base + (long long)r0g * 1025 + i] = val;
    else ((bf16*)outv)[base + (long long)r0g * 1025 + i] = __float2bfloat16(val);
  }
  if (blk == 0) {
    const float un = su[1024];
    for (int cc = t; cc < 1025; cc += 512) {
      float val = alpha + un + sv[cc] - NORM;
      if (f) ((float*)outv)[base + (long long)1024 * 1025 + cc] = val;
      else ((bf16*)outv)[base + (long long)1024 * 1025 + cc] = __float2bfloat16(val);
    }
  }
}

// ================================================================== launch
extern "C" void kernel_launch(void* const* d_in, const int* in_sizes, int n_in,
                              void* d_out, int out_size, void* d_ws, size_t ws_size,
                              hipStream_t stream) {
  const void* scores = d_in[0];
  const void* distance = d_in[1];
  const void* enc_W0 = d_in[2];
  const void* enc_b0 = d_in[3];
  const void* enc_bn = d_in[4];
  const void* enc_W1 = d_in[5];
  const void* enc_b1 = d_in[6];
  const void* gnn_Wqkv = d_in[7];
  const void* gnn_bqkv = d_in[8];
  const void* gnn_Wm = d_in[9];
  const void* gnn_bm = d_in[10];
  const void* gnn_W1 = d_in[11];
  const void* gnn_b1 = d_in[12];
  const void* gnn_bn = d_in[13];
  const void* gnn_W2 = d_in[14];
  const void* gnn_b2 = d_in[15];
  const void* final_W = d_in[16];
  const void* final_b = d_in[17];
  const void* alpha = d_in[18];
  (void)in_sizes; (void)n_in; (void)out_size; (void)ws_size;

  char* ws = (char*)d_ws;
  size_t off = 0;
  auto alloc = [&](size_t bytes) -> void* {
    void* p = ws + off;
    off += (bytes + 255) & ~(size_t)255;
    return p;
  };
  int* flag = (int*)alloc(256);
  int* nvA = (int*)alloc(256);
  float* sn = (float*)alloc(20000 * 4);
  int* idxO = (int*)alloc(4096 * 4);
  float* valsO = (float*)alloc(4096 * 4);
  float* maskO = (float*)alloc(4096 * 4);
  float* emb = (float*)alloc((size_t)4096 * 256 * 4);
  float* Wp = (float*)alloc((size_t)65536 * 4);
  float* T0 = (float*)alloc((size_t)4096 * 256 * 4);
  float* X = (float*)alloc((size_t)4096 * 256 * 4);
  float* QKVh = (float*)alloc((size_t)3 * 4194304 * 4);
  float* meanV = (float*)alloc(16 * 64 * 4);
  float* msgb = (float*)alloc((size_t)4096 * 256 * 4);
  float* M2 = (float*)alloc((size_t)4096 * 256 * 4);
  float* Y1 = (float*)alloc((size_t)4096 * 512 * 4);
  float* MD = (float*)alloc((size_t)4096 * 256 * 4);
  float* Cpl = (float*)alloc((size_t)4 * 1050625 * 4);
  float* u = (float*)alloc(4100 * 4);
  float* v = (float*)alloc(4100 * 4);
  unsigned* flagsS = (unsigned*)alloc(256 * 4);

  hipMemsetAsync(u, 0, 4100 * 4, stream);
  hipMemsetAsync(v, 0, 4100 * 4, stream);
  hipMemsetAsync(flagsS, 0, 256 * 4, stream);

  static bool attrSet = false;
  if (!attrSet) {
    hipFuncSetAttribute(reinterpret_cast<const void*>(&k_sinkhorn),
                        hipFuncAttributeMaxDynamicSharedMemorySize, 139600);
    attrSet = true;
  }

  const dim3 b256(256);
  k_detect<<<1, b256, 0, stream>>>(distance, flag);
  k_nms<<<4, 512, 0, stream>>>(scores, flag, sn);
  k_sort<<<4, 1024, 0, stream>>>(sn, idxO, valsO, maskO, nvA);
  k_emb<<<4096, b256, 0, stream>>>(idxO, valsO, distance, emb, flag);
  k_padw0<<<256, b256, 0, stream>>>(enc_W0, Wp, flag);

  gemm_mf<1, false, 1><<<dim3(4, 64, 1), b256, 0, stream>>>(
      emb, nullptr, 256, Wp, enc_b0, enc_bn, T0, 256, 256, 256, 1.f,
      0, 0, 0, 0, 0, 0, flag);
  gemm_mf<0, false, 0><<<dim3(4, 64, 1), b256, 0, stream>>>(
      T0, nullptr, 256, enc_W1, enc_b1, nullptr, X, 256, 256, 256, 1.f,
      0, 0, 0, 0, 0, 0, flag);

  for (int l = 0; l < 4; l++) {
    gemm_mf<3, false, 0><<<dim3(12, 64, 1), b256, 0, stream>>>(
        X, nullptr, 256, gnn_Wqkv, gnn_bqkv, nullptr, QKVh, 0, 768, 256, 1.f,
        0, 0, 0, (long long)l * 196608, (long long)l * 768, 0, flag);
    k_meanv<<<16, b256, 0, stream>>>(QKVh, meanV);
    k_attn<<<dim3(16, 4, 4), b256, 0, stream>>>(QKVh, maskO, nvA, meanV, msgb);
    gemm_mf<0, false, 0><<<dim3(4, 64, 1), b256, 0, stream>>>(
        msgb, nullptr, 256, gnn_Wm, gnn_bm, nullptr, M2, 256, 256, 256, 1.f,
        0, 0, 0, (long long)l * 65536, (long long)l * 256, 0, flag);
    gemm_mf<1, true, 0><<<dim3(8, 64, 1), b256, 0, stream>>>(
        X, M2, 256, gnn_W1, gnn_b1, gnn_bn, Y1, 512, 512, 512, 1.f,
        0, 0, 0, (long long)l * 262144, (long long)l * 512, (long long)l * 2048, flag);
    gemm_mf<2, false, 0><<<dim3(4, 64, 1), b256, 0, stream>>>(
        Y1, nullptr, 512, gnn_W2, gnn_b2, nullptr, X, 256, 256, 512, 1.f,
        0, 0, 0, (long long)l * 131072, (long long)l * 256, 0, flag);
  }
  gemm_mf<0, false, 0><<<dim3(4, 64, 1), b256, 0, stream>>>(
      X, nullptr, 256, final_W, final_b, nullptr, MD, 256, 256, 256, 1.f,
      0, 0, 0, 0, 0, 0, flag);
  gemm_mf<4, false, 1><<<dim3(16, 16, 4), b256, 0, stream>>>(
      MD, nullptr, 256, MD, nullptr, nullptr, Cpl, 1025, 1024, 256, 0.0625f,
      262144, 262144, 1050625, 0, 0, 0, flag);
  k_border<<<16, b256, 0, stream>>>(Cpl, alpha, flag);
  k_sinkhorn<<<128, 512, 139600, stream>>>(Cpl, alpha, u, v, flagsS, d_out, flag);
}

// Round 7
// 1821.445 us; speedup vs baseline: 3.6920x; 1.1520x over previous
//
#include <hip/hip_runtime.h>
#include <hip/hip_bf16.h>

typedef __hip_bfloat16 bf16;
typedef __attribute__((ext_vector_type(8))) short short8;
typedef __attribute__((ext_vector_type(4))) float f32x4;
#define DEV __device__ __forceinline__

// Adaptive input load: flag==1 -> fp32 data, flag==0 -> bf16 data.
DEV float ldin(const void* p, long long i, int f) {
  return f ? ((const float*)p)[i]
           : __uint_as_float(((unsigned)((const unsigned short*)p)[i]) << 16);
}
DEV unsigned short f2bf(float x) {  // RNE f32->bf16
  unsigned u = __float_as_uint(x);
  return (unsigned short)((u + 0x7FFFu + ((u >> 16) & 1u)) >> 16);
}
DEV float bf2f(unsigned short h) { return __uint_as_float((unsigned)h << 16); }

// -------------------------------------------- fused detect + NMS + top-k sort
DEV void mp5f(const float* in, float* tmp, float* out, int t) {
  for (int i = t; i < 5000; i += 1024) {
    int y = i / 100, x = i % 100;
    int x0 = x - 2 < 0 ? 0 : x - 2, x1 = x + 2 > 99 ? 99 : x + 2;
    float m = -INFINITY;
    for (int xx = x0; xx <= x1; xx++) m = fmaxf(m, in[y * 100 + xx]);
    tmp[i] = m;
  }
  __syncthreads();
  for (int i = t; i < 5000; i += 1024) {
    int y = i / 100, x = i % 100;
    int y0 = y - 2 < 0 ? 0 : y - 2, y1 = y + 2 > 49 ? 49 : y + 2;
    float m = -INFINITY;
    for (int yy = y0; yy <= y1; yy++) m = fmaxf(m, tmp[yy * 100 + x]);
    out[i] = m;
  }
  __syncthreads();
}

__global__ __launch_bounds__(1024) void k_front(
    const void* __restrict__ scores, const void* __restrict__ dist,
    int* __restrict__ flagO, int* __restrict__ idxO, float* __restrict__ valsO,
    float* __restrict__ maskO, int* __restrict__ nvp) {
  extern __shared__ float lds[];
  float* S = lds;                 // 5000
  float* MK = lds + 5000;         // 5000
  float* Z = lds + 10000;         // 20000 scratch (T,P,SP,SS / keys)
  float* T = Z;
  float* P = Z + 5000;
  float* SP = Z + 10000;
  float* SS = Z + 15000;
  unsigned long long* keys = (unsigned long long*)(lds + 10000);  // 8192 u64
  __shared__ int bad, cnt;
  const int bb = blockIdx.x, t = threadIdx.x;
  if (t == 0) { bad = 0; cnt = 0; }
  __syncthreads();
  {  // dtype detect (each block computes its own copy)
    int c = 0;
    const unsigned short* p = (const unsigned short*)dist;
    for (int i = t; i < 65536; i += 1024) {
      unsigned e = (p[i] >> 7) & 0xFF;
      if (e >= 0x86) c++;
    }
    atomicAdd(&bad, c);
  }
  __syncthreads();
  const int f = (bad > 100) ? 1 : 0;
  if (bb == 0 && t == 0) *flagO = f;
  for (int i = t; i < 5000; i += 1024) S[i] = ldin(scores, bb * 5000 + i, f);
  __syncthreads();
  mp5f(S, T, P, t);
  for (int i = t; i < 5000; i += 1024) MK[i] = (S[i] == P[i]) ? 1.f : 0.f;
  __syncthreads();
  for (int r = 0; r < 2; r++) {
    mp5f(MK, T, P, t);
    for (int i = t; i < 5000; i += 1024) {
      SP[i] = (P[i] > 0.f) ? 1.f : 0.f;
      SS[i] = (SP[i] != 0.f) ? 0.f : S[i];
    }
    __syncthreads();
    mp5f(SS, T, P, t);
    for (int i = t; i < 5000; i += 1024)
      if (MK[i] == 0.f) MK[i] = ((SS[i] == P[i]) && (SP[i] == 0.f)) ? 1.f : 0.f;
    __syncthreads();
  }
  // build sort keys (overwrites scratch; S/MK preserved)
  for (int i = t; i < 8192; i += 1024) {
    unsigned long long kk;
    if (i < 5000) {
      float v = (MK[i] != 0.f) ? S[i] : 0.f;
      unsigned vb = __float_as_uint(v);
      kk = ((unsigned long long)vb << 32) | (unsigned)(0xFFFFFFFFu - (unsigned)i);
    } else {
      kk = 0ull;
    }
    keys[i] = ~kk;
  }
  __syncthreads();
  for (int k = 2; k <= 8192; k <<= 1) {
    for (int j = k >> 1; j > 0; j >>= 1) {
      for (int i = t; i < 8192; i += 1024) {
        int ixj = i ^ j;
        if (ixj > i) {
          unsigned long long a = keys[i], b = keys[ixj];
          bool up = ((i & k) == 0);
          if (up ? (a > b) : (a < b)) { keys[i] = b; keys[ixj] = a; }
        }
      }
      __syncthreads();
    }
  }
  {
    unsigned long long kk = ~keys[t];
    unsigned idx = 0xFFFFFFFFu - (unsigned)(kk & 0xFFFFFFFFu);
    float v = __uint_as_float((unsigned)(kk >> 32));
    idxO[bb * 1024 + t] = (int)idx;
    valsO[bb * 1024 + t] = v;
    bool valid = (v > 0.015f);
    maskO[bb * 1024 + t] = valid ? 1.f : 0.f;
    unsigned long long bal = __ballot(valid);
    if ((t & 63) == 0) atomicAdd(&cnt, (int)__popcll(bal));
  }
  __syncthreads();
  if (t == 0) nvp[bb] = cnt;
}

// -------------------------------- weight prep: split all weights to hi/lo bf16
// Segments (elem offsets): W0pad 0 | We1 65536 | Wqkv(row-perm) 131072 |
// Wm(col-perm) 917504 | W1 1179648 | W2 2228224 | Wf 2752512 | end 2818048
__global__ void k_prep(const void* __restrict__ W0, const void* __restrict__ W1e,
                       const void* __restrict__ Wqkv, const void* __restrict__ Wm,
                       const void* __restrict__ W1g, const void* __restrict__ W2g,
                       const void* __restrict__ Wf, unsigned short* __restrict__ WH,
                       unsigned short* __restrict__ WL, const int* __restrict__ flagp) {
  const int f = *flagp;
  long long g = (long long)blockIdx.x * 256 + threadIdx.x;
  float val;
  if (g < 65536) {
    int r = (int)(g >> 8), c = (int)(g & 255);
    val = (c < 235) ? ldin(W0, (long long)r * 235 + c, f) : 0.f;
  } else if (g < 131072) {
    val = ldin(W1e, g - 65536, f);
  } else if (g < 917504) {
    long long L = g - 131072;
    int R = (int)(L >> 8), k = (int)(L & 255);
    int l = R / 768, rp = R % 768;
    int qkv = rp >> 8, cp = rp & 255, h = cp >> 6, d = cp & 63;
    val = ldin(Wqkv, ((long long)((l * 3 + qkv) * 256 + d * 4 + h)) * 256 + k, f);
  } else if (g < 1179648) {
    long long L = g - 917504;
    int n = (int)(L >> 8), kp = (int)(L & 255);
    int k = (kp & 63) * 4 + (kp >> 6);
    val = ldin(Wm, (long long)n * 256 + k, f);
  } else if (g < 2228224) {
    val = ldin(W1g, g - 1179648, f);
  } else if (g < 2752512) {
    val = ldin(W2g, g - 2228224, f);
  } else {
    val = ldin(Wf, g - 2752512, f);
  }
  unsigned short h_ = f2bf(val);
  WH[g] = h_;
  WL[g] = f2bf(val - bf2f(h_));
}

// --------------------------------------------------------- embedding (planes)
__global__ void k_emb(const int* __restrict__ idxO, const float* __restrict__ valsO,
                      const void* __restrict__ distance,
                      unsigned short* __restrict__ eH, unsigned short* __restrict__ eL,
                      const int* __restrict__ flagp) {
  const int f = *flagp;
  const int vtx = blockIdx.x;
  const int bb = vtx >> 10, i = vtx & 1023;
  const int t = threadIdx.x;
  const int id = idxO[bb * 1024 + i];
  const int cy = id / 100, cx = id % 100;
  const float nvx = ((float)cx - 50.0f + 0.5f) / 100.0f;
  const float nvy = ((float)cy - 25.0f + 0.5f) / 50.0f;
  const int c = t;
  float val;
  if (c == 0) val = nvx;
  else if (c == 1) val = nvy;
  else if (c < 42) {
    int d = c - 2, fq = d >> 2, r = d & 3;
    float freq = (float)(1 << fq);
    float ang = ((r == 0 || r == 2) ? nvx : nvy) * freq;
    val = (r < 2) ? sinf(ang) : cosf(ang);
  } else if (c == 42) {
    val = valsO[bb * 1024 + i];
  } else if (c < 235) {
    int d = c - 43, cls = d >> 6, ii = (d >> 3) & 7, jj = d & 7;
    val = ldin(distance,
               (((long long)bb * 3 + cls) * 400 + (cy * 8 + ii)) * 800 + (cx * 8 + jj), f);
  } else {
    val = 0.f;
  }
  unsigned short h_ = f2bf(val);
  eH[(long long)vtx * 256 + c] = h_;
  eL[(long long)vtx * 256 + c] = f2bf(val - bf2f(h_));
}

// ----------------------------------------------- plane MFMA GEMM (NT, bf16x3)
// out[m,n] = sum_k A[m,k]*W[n,k]; A,W as hi/lo bf16 planes. 64x64 tile, BK=32.
// MODE: 0 bias->planes; 1 bias,BN,ReLU->planes; 2 bias+resid->f32+planes;
// 3 qkv-bias-map->f32(ldc768); 4 *scale->f32(gram); 5 bias->f32+planes.
// W3F: force 3rd mfma (Ah*Bl) regardless of runtime flag.
template <int MODE, bool SPLIT, bool W3F>
__global__ __launch_bounds__(256) void gemm_pl(
    const unsigned short* __restrict__ Ah, const unsigned short* __restrict__ Al,
    const unsigned short* __restrict__ A2h, const unsigned short* __restrict__ A2l,
    int lda, const unsigned short* __restrict__ WHp,
    const unsigned short* __restrict__ WLp, const void* __restrict__ bias,
    const void* __restrict__ bn, float* __restrict__ CoutF,
    unsigned short* __restrict__ CoutH, unsigned short* __restrict__ CoutL,
    int ldc, int N, int K, float scale,
    long long aBatch, long long wBatch, long long cBatch,
    long long wOff, long long bOff, long long bnOff,
    const int* __restrict__ flagp) {
  const int rf = *flagp;
  const bool w3 = W3F || (rf != 0);
  const unsigned short* Ahp = Ah + (long long)blockIdx.z * aBatch;
  const unsigned short* Alp = Al + (long long)blockIdx.z * aBatch;
  CoutF += (long long)blockIdx.z * cBatch;
  const long long wb = wOff + (long long)blockIdx.z * wBatch;
  __shared__ unsigned short AH[2112], AL[2112], BH[2112], BL[2112];
  const int t = threadIdx.x;
  const int m0 = blockIdx.y * 64, n0 = blockIdx.x * 64;
  const int w = t >> 6, lane = t & 63, quad = lane >> 4, l15 = lane & 15;
  ushort4 rah[2], ral[2], rbh[2], rbl[2];
  auto loadT = [&](int k0) {
#pragma unroll
    for (int i = 0; i < 2; i++) {
      int id = t + (i << 8);
      int m = id >> 3, k4 = (id & 7) << 2;
      int kc = k0 + k4;
      const unsigned short* ph = Ahp;
      const unsigned short* pl = Alp;
      int kk = kc;
      if (SPLIT && kc >= 256) { ph = A2h; pl = A2l; kk = kc - 256; }
      long long ai = (long long)(m0 + m) * lda + kk;
      rah[i] = *(const ushort4*)&ph[ai];
      ral[i] = *(const ushort4*)&pl[ai];
      long long wi = wb + (long long)(n0 + m) * K + kc;
      rbh[i] = *(const ushort4*)&WHp[wi];
      rbl[i] = *(const ushort4*)&WLp[wi];
    }
  };
  auto storeT = [&]() {
#pragma unroll
    for (int i = 0; i < 2; i++) {
      int id = t + (i << 8);
      int m = id >> 3, k4 = (id & 7) << 2;
      int q = k4 >> 3, j0 = k4 & 7;
      int li = (q * 66 + m) * 8 + j0;  // pad 64->66: q-stride shifts 8 banks
      *(ushort4*)&AH[li] = rah[i];
      *(ushort4*)&AL[li] = ral[i];
      *(ushort4*)&BH[li] = rbh[i];
      *(ushort4*)&BL[li] = rbl[i];
    }
  };
  f32x4 acc[4];
#pragma unroll
  for (int c = 0; c < 4; c++) acc[c] = (f32x4){0.f, 0.f, 0.f, 0.f};
  loadT(0);
  const int mr = w * 16 + l15;
  for (int k0 = 0; k0 < K; k0 += 32) {
    storeT();
    __syncthreads();
    if (k0 + 32 < K) loadT(k0 + 32);
    short8 fa = *(const short8*)&AH[(quad * 66 + mr) * 8];
    short8 fal = *(const short8*)&AL[(quad * 66 + mr) * 8];
#pragma unroll
    for (int cb = 0; cb < 4; cb++) {
      int nr = cb * 16 + l15;
      short8 fb = *(const short8*)&BH[(quad * 66 + nr) * 8];
      acc[cb] = __builtin_amdgcn_mfma_f32_16x16x32_bf16(fa, fb, acc[cb], 0, 0, 0);
      acc[cb] = __builtin_amdgcn_mfma_f32_16x16x32_bf16(fal, fb, acc[cb], 0, 0, 0);
      if (w3) {
        short8 fbl = *(const short8*)&BL[(quad * 66 + nr) * 8];
        acc[cb] = __builtin_amdgcn_mfma_f32_16x16x32_bf16(fa, fbl, acc[cb], 0, 0, 0);
      }
    }
    __syncthreads();
  }
#pragma unroll
  for (int cb = 0; cb < 4; cb++) {
    const int n = n0 + cb * 16 + l15;
    float bv = 0.f, g = 0.f, bt = 0.f, mu = 0.f, vr = 0.f;
    if (MODE != 4) {
      long long bidx;
      if (MODE == 3) {
        int c = n & 255;
        bidx = bOff + (long long)(n >> 8) * 256 + (c & 63) * 4 + (c >> 6);
      } else {
        bidx = bOff + n;
      }
      bv = ldin(bias, bidx, rf);
    }
    if (MODE == 1) {
      g = ldin(bn, bnOff + n, rf);
      bt = ldin(bn, bnOff + N + n, rf);
      mu = ldin(bn, bnOff + 2 * N + n, rf);
      vr = ldin(bn, bnOff + 3 * N + n, rf);
    }
#pragma unroll
    for (int r = 0; r < 4; r++) {
      const int m = m0 + w * 16 + quad * 4 + r;
      float v = acc[cb][r];
      if (MODE == 4) v *= scale;
      else v += bv;
      if (MODE == 1) {
        v = g * (v - mu) / sqrtf(vr + 1e-5f) + bt;
        v = fmaxf(v, 0.f);
      }
      if (MODE == 2) v += CoutF[(long long)m * ldc + n];
      if (MODE == 2 || MODE == 3 || MODE == 4 || MODE == 5)
        CoutF[(long long)m * ldc + n] = v;
      if (MODE == 0 || MODE == 1 || MODE == 2 || MODE == 5) {
        unsigned short hh = f2bf(v);
        CoutH[(long long)m * ldc + n] = hh;
        CoutL[(long long)m * ldc + n] = f2bf(v - bf2f(hh));
      }
    }
  }
}

// ------------------------------------------------ per-(b,h) mean of V rows
__global__ __launch_bounds__(256) void k_meanv(const float* __restrict__ QKV,
                                               float* __restrict__ meanV) {
  const int bh = blockIdx.x;  // 0..15
  const int t = threadIdx.x;
  const int c4 = t >> 6, d = t & 63;
  __shared__ float part[4][64];
  const float* Vb = QKV + (long long)(bh >> 2) * 1024 * 768 + 512 + (bh & 3) * 64;
  float s = 0.f;
  for (int r = c4 * 256; r < (c4 + 1) * 256; r++) s += Vb[(long long)r * 768 + d];
  part[c4][d] = s;
  __syncthreads();
  if (c4 == 0)
    meanV[bh * 64 + d] =
        (part[0][d] + part[1][d] + part[2][d] + part[3][d]) * (1.f / 1024.f);
}

// -------------------------------------------------- flash-style attention
// QKV natural [m][768] h-major (cols qkv*256 + h*64 + d). msg out as planes.
__global__ __launch_bounds__(256) void k_attn(
    const float* __restrict__ QKV, const float* __restrict__ maskf,
    const int* __restrict__ nvp, const float* __restrict__ meanV,
    unsigned short* __restrict__ msgH, unsigned short* __restrict__ msgL) {
  const int qt = blockIdx.x, h = blockIdx.y, bb = blockIdx.z;
  const int t = threadIdx.x;
  const int q2 = t >> 3, j8 = t & 7;
  __shared__ float Qst[64][68];
  __shared__ float Kst[64][68];
  __shared__ float Vs[64][72];
  __shared__ float Pst[64][68];
  __shared__ float qm[64], km[64];
  const float* Qb = QKV + (long long)bb * 1024 * 768 + h * 64;
  const float* Kb = Qb + 256;
  const float* Vb = Qb + 512;
  const int q0 = qt * 64;
  const int nv = nvp[bb];
  const int nt = (nv + 63) >> 6;
  float mi[2] = {-INFINITY, -INFINITY};
  float li[2] = {0.f, 0.f};
  float o[2][8] = {};
  if (q0 < nv) {
#pragma unroll
    for (int i = 0; i < 4; i++) {
      int id = t + i * 256;
      int q = id >> 4, d4 = (id & 15) << 2;
      float4 qv = *(const float4*)&Qb[(long long)(q0 + q) * 768 + d4];
      Qst[d4][q] = qv.x; Qst[d4 + 1][q] = qv.y;
      Qst[d4 + 2][q] = qv.z; Qst[d4 + 3][q] = qv.w;
    }
    if (t < 64) qm[t] = maskf[bb * 1024 + q0 + t];
    __syncthreads();
    const float qmr[2] = {qm[2 * q2], qm[2 * q2 + 1]};
    for (int kt = 0; kt < nt; kt++) {
      const int k0 = kt * 64;
      __syncthreads();
#pragma unroll
      for (int i = 0; i < 4; i++) {
        int id = t + i * 256;
        int n = id >> 4, d4 = (id & 15) << 2;
        float4 kv = *(const float4*)&Kb[(long long)(k0 + n) * 768 + d4];
        Kst[d4][n] = kv.x; Kst[d4 + 1][n] = kv.y;
        Kst[d4 + 2][n] = kv.z; Kst[d4 + 3][n] = kv.w;
        float4 vvv = *(const float4*)&Vb[(long long)(k0 + n) * 768 + d4];
        *(float4*)&Vs[n][d4] = vvv;
      }
      if (t < 64) km[t] = maskf[bb * 1024 + k0 + t];
      __syncthreads();
      float kmr[8];
#pragma unroll
      for (int kk = 0; kk < 8; kk++) kmr[kk] = km[8 * j8 + kk];
      float s[2][8] = {};
      for (int d = 0; d < 64; d++) {
        float2 qv = *(const float2*)&Qst[d][2 * q2];
        float4 ka = *(const float4*)&Kst[d][8 * j8];
        float4 kb = *(const float4*)&Kst[d][8 * j8 + 4];
        s[0][0] = fmaf(qv.x, ka.x, s[0][0]); s[0][1] = fmaf(qv.x, ka.y, s[0][1]);
        s[0][2] = fmaf(qv.x, ka.z, s[0][2]); s[0][3] = fmaf(qv.x, ka.w, s[0][3]);
        s[0][4] = fmaf(qv.x, kb.x, s[0][4]); s[0][5] = fmaf(qv.x, kb.y, s[0][5]);
        s[0][6] = fmaf(qv.x, kb.z, s[0][6]); s[0][7] = fmaf(qv.x, kb.w, s[0][7]);
        s[1][0] = fmaf(qv.y, ka.x, s[1][0]); s[1][1] = fmaf(qv.y, ka.y, s[1][1]);
        s[1][2] = fmaf(qv.y, ka.z, s[1][2]); s[1][3] = fmaf(qv.y, ka.w, s[1][3]);
        s[1][4] = fmaf(qv.y, kb.x, s[1][4]); s[1][5] = fmaf(qv.y, kb.y, s[1][5]);
        s[1][6] = fmaf(qv.y, kb.z, s[1][6]); s[1][7] = fmaf(qv.y, kb.w, s[1][7]);
      }
#pragma unroll
      for (int qq = 0; qq < 2; qq++) {
        float rm = -INFINITY;
#pragma unroll
        for (int kk = 0; kk < 8; kk++) {
          float val = (qmr[qq] * kmr[kk] == 0.f) ? -1e9f : s[qq][kk] * 0.125f;
          s[qq][kk] = val;
          rm = fmaxf(rm, val);
        }
        rm = fmaxf(rm, __shfl_xor(rm, 1));
        rm = fmaxf(rm, __shfl_xor(rm, 2));
        rm = fmaxf(rm, __shfl_xor(rm, 4));
        float nm = fmaxf(mi[qq], rm);
        float al = __expf(mi[qq] - nm);
        mi[qq] = nm;
        float sum = 0.f;
#pragma unroll
        for (int kk = 0; kk < 8; kk++) {
          float p = __expf(s[qq][kk] - nm);
          Pst[8 * j8 + kk][2 * q2 + qq] = p;
          sum += p;
        }
        sum += __shfl_xor(sum, 1);
        sum += __shfl_xor(sum, 2);
        sum += __shfl_xor(sum, 4);
        li[qq] = li[qq] * al + sum;
#pragma unroll
        for (int dd = 0; dd < 8; dd++) o[qq][dd] *= al;
      }
      __syncthreads();
      for (int m = 0; m < 64; m++) {
        float2 pv = *(const float2*)&Pst[m][2 * q2];
        float4 va = *(const float4*)&Vs[m][8 * j8];
        float4 vb = *(const float4*)&Vs[m][8 * j8 + 4];
        o[0][0] = fmaf(pv.x, va.x, o[0][0]); o[0][1] = fmaf(pv.x, va.y, o[0][1]);
        o[0][2] = fmaf(pv.x, va.z, o[0][2]); o[0][3] = fmaf(pv.x, va.w, o[0][3]);
        o[0][4] = fmaf(pv.x, vb.x, o[0][4]); o[0][5] = fmaf(pv.x, vb.y, o[0][5]);
        o[0][6] = fmaf(pv.x, vb.z, o[0][6]); o[0][7] = fmaf(pv.x, vb.w, o[0][7]);
        o[1][0] = fmaf(pv.y, va.x, o[1][0]); o[1][1] = fmaf(pv.y, va.y, o[1][1]);
        o[1][2] = fmaf(pv.y, va.z, o[1][2]); o[1][3] = fmaf(pv.y, va.w, o[1][3]);
        o[1][4] = fmaf(pv.y, vb.x, o[1][4]); o[1][5] = fmaf(pv.y, vb.y, o[1][5]);
        o[1][6] = fmaf(pv.y, vb.z, o[1][6]); o[1][7] = fmaf(pv.y, vb.w, o[1][7]);
      }
    }
  }
#pragma unroll
  for (int qq = 0; qq < 2; qq++) {
    const int q = q0 + 2 * q2 + qq;
    const long long idx = ((long long)bb * 1024 + q) * 256 + h * 64 + 8 * j8;
    const float inv = (q < nv) ? (1.f / li[qq]) : 0.f;
#pragma unroll
    for (int dd = 0; dd < 8; dd++) {
      float val = (q < nv) ? o[qq][dd] * inv
                           : meanV[((bb * 4 + h) << 6) + 8 * j8 + dd];
      unsigned short hh = f2bf(val);
      msgH[idx + dd] = hh;
      msgL[idx + dd] = f2bf(val - bf2f(hh));
    }
  }
}

// ------------------------------------------------------------- border (col 1024)
__global__ void k_border(float* __restrict__ C, const void* __restrict__ alpha,
                         const int* __restrict__ flagp) {
  const int f = *flagp;
  int g = blockIdx.x * 256 + threadIdx.x;
  if (g >= 4096) return;
  float a = ldin(alpha, 0, f);
  int bb = g >> 10, r = g & 1023;
  C[(long long)bb * 1050625 + (long long)r * 1025 + 1024] = a;
}

// -------------------------------------------------------------- Sinkhorn
// 4 groups x 32 blocks x 512 thr; expC = exp(C - rowmax) in LDS. Fixed-shift
// LSE (u,v bounded ~|40| -> exp safe in fp32): no block-wide max reduction.
__global__ __launch_bounds__(512) void k_sinkhorn(
    const float* __restrict__ C, const void* __restrict__ alphap,
    float* u, float* v, unsigned* flags, void* __restrict__ outv,
    const int* __restrict__ flagp) {
  extern __shared__ float lds[];
  float* expC = lds;          // 32*1025
  float* sv = lds + 32800;    // 1025
  float* su = sv + 1025;      // 1025
  float* mc = su + 1025;      // 32
  float* wredd = mc + 32;     // 8
  int* qf = (int*)(wredd + 8);
  const int f = *flagp;
  const int bb = blockIdx.x >> 5;
  const int blk = blockIdx.x & 31;
  const int t = threadIdx.x;
  const int wid = t >> 6, lane = t & 63;
  const int r0g = blk << 5;
  const int rw = wid << 2;
  const float alpha = ldin(alphap, 0, f);
  const float* Cb = C + (long long)bb * 1050625;
  float* ub = u + bb * 1025;
  float* vb = v + bb * 1025;
  unsigned* fl = flags + bb * 64;
  const float NORM = -7.624619086159398f;  // -log(2048)
  const float BIN = -0.6931471805599453f;  // log(1024)-log(2048)
  for (int i = t; i < 32800; i += 512) expC[i] = Cb[(long long)r0g * 1025 + i];
  __syncthreads();
#pragma unroll
  for (int j = 0; j < 4; j++) {
    const float* cr = expC + (rw + j) * 1025;
    float mx = -INFINITY;
#pragma unroll
    for (int i = 0; i < 17; i++) {
      int col = (i << 6) + lane;
      if (col <= 1024) mx = fmaxf(mx, cr[col]);
    }
#pragma unroll
    for (int o = 32; o; o >>= 1) mx = fmaxf(mx, __shfl_xor(mx, o, 64));
    if (lane == 0) mc[rw + j] = mx;
  }
  __syncthreads();
  for (int i = t; i < 32800; i += 512) {
    int r = i / 1025;
    expC[i] = __expf(expC[i] - mc[r]);
  }
  __syncthreads();
  float prevU[4] = {0, 0, 0, 0}, prevV[4] = {0, 0, 0, 0};
  float prevAU = 0.f, prevAV = 0.f;
  for (int half = 0; half < 200; half++) {
    float* dst = (half & 1) ? vb : ub;
    const float* srcf = (half & 1) ? ub : vb;
    {
      unsigned long long d = __hip_atomic_load(
          (const unsigned long long*)srcf + t, __ATOMIC_RELAXED, __HIP_MEMORY_SCOPE_AGENT);
      sv[2 * t] = __uint_as_float((unsigned)d);
      sv[2 * t + 1] = __uint_as_float((unsigned)(d >> 32));
      if (t == 0)
        sv[1024] = __uint_as_float(__hip_atomic_load(
            (const unsigned*)(srcf + 1024), __ATOMIC_RELAXED, __HIP_MEMORY_SCOPE_AGENT));
    }
    __syncthreads();
    float svr[17];
#pragma unroll
    for (int i = 0; i < 17; i++) {
      int col = (i << 6) + lane;
      svr[i] = (col <= 1024) ? __expf(sv[col]) : 0.f;
    }
    float wd = 0.f;
    float* prev = (half & 1) ? prevV : prevU;
    float dsts[4];
#pragma unroll
    for (int j = 0; j < 4; j++) {
      const float* cr = expC + (rw + j) * 1025;
      float s = 0.f;
#pragma unroll
      for (int i = 0; i < 17; i++) {
        int col = (i << 6) + lane;
        int cc = (col <= 1024) ? col : 0;  // svr=0 masks tail
        s = fmaf(cr[cc], svr[i], s);
      }
#pragma unroll
      for (int o = 32; o; o >>= 1) s += __shfl_xor(s, o, 64);
      float nval = NORM - (mc[rw + j] + __logf(s));
      dsts[j] = nval;
      wd = fmaxf(wd, fabsf(nval - prev[j]));
      prev[j] = nval;
    }
    if (lane == 0) {
      unsigned long long p0 = ((unsigned long long)__float_as_uint(dsts[1]) << 32) |
                              __float_as_uint(dsts[0]);
      unsigned long long p1 = ((unsigned long long)__float_as_uint(dsts[3]) << 32) |
                              __float_as_uint(dsts[2]);
      __hip_atomic_store((unsigned long long*)(dst + r0g + rw), p0,
                         __ATOMIC_RELAXED, __HIP_MEMORY_SCOPE_AGENT);
      __hip_atomic_store((unsigned long long*)(dst + r0g + rw + 2), p1,
                         __ATOMIC_RELAXED, __HIP_MEMORY_SCOPE_AGENT);
    }
    if (blk == 0 && wid == 0) {  // alpha row
      float s = 0.f;
#pragma unroll
      for (int i = 0; i < 17; i++) s += svr[i];
#pragma unroll
      for (int o = 32; o; o >>= 1) s += __shfl_xor(s, o, 64);
      float nval = BIN - (alpha + __logf(s));
      float* pa = (half & 1) ? &prevAV : &prevAU;
      wd = fmaxf(wd, fabsf(nval - *pa));
      *pa = nval;
      if (lane == 0)
        __hip_atomic_store((unsigned*)(dst + 1024), __float_as_uint(nval),
                           __ATOMIC_RELAXED, __HIP_MEMORY_SCOPE_AGENT);
    }
    if (lane == 0) wredd[wid] = wd;
    __syncthreads();
    if (wid == 0) {
      if (lane == 0) {
        float bmax = wredd[0];
#pragma unroll
        for (int k = 1; k < 8; k++) bmax = fmaxf(bmax, wredd[k]);
        unsigned val = ((unsigned)(half + 1) << 1) | (bmax < 5e-4f ? 1u : 0u);
        __hip_atomic_store(fl + ((half & 1) << 5) + blk, val, __ATOMIC_RELEASE,
                           __HIP_MEMORY_SCOPE_AGENT);
      }
      int q = 0;
      if (lane < 32) {
        const unsigned tgt = (unsigned)(half + 1) << 1;
        unsigned vv;
        for (;;) {
          vv = __hip_atomic_load(fl + ((half & 1) << 5) + lane, __ATOMIC_ACQUIRE,
                                 __HIP_MEMORY_SCOPE_AGENT);
          if (vv >= tgt) break;
          __builtin_amdgcn_s_sleep(1);
        }
        unsigned long long cb_ = __ballot((vv & 1u) != 0u);
        q = (((unsigned)cb_) == 0xFFFFFFFFu && half >= 40 && (half & 1)) ? 1 : 0;
        if (lane == 0) *qf = q;
      }
    }
    __syncthreads();
    if (*qf) break;
  }
  {
    unsigned long long du = __hip_atomic_load(
        (const unsigned long long*)ub + t, __ATOMIC_RELAXED, __HIP_MEMORY_SCOPE_AGENT);
    unsigned long long dv = __hip_atomic_load(
        (const unsigned long long*)vb + t, __ATOMIC_RELAXED, __HIP_MEMORY_SCOPE_AGENT);
    su[2 * t] = __uint_as_float((unsigned)du);
    su[2 * t + 1] = __uint_as_float((unsigned)(du >> 32));
    sv[2 * t] = __uint_as_float((unsigned)dv);
    sv[2 * t + 1] = __uint_as_float((unsigned)(dv >> 32));
    if (t == 0) {
      su[1024] = __uint_as_float(__hip_atomic_load(
          (const unsigned*)(ub + 1024), __ATOMIC_RELAXED, __HIP_MEMORY_SCOPE_AGENT));
      sv[1024] = __uint_as_float(__hip_atomic_load(
          (const unsigned*)(vb + 1024), __ATOMIC_RELAXED, __HIP_MEMORY_SCOPE_AGENT));
    }
  }
  __syncthreads();
  const long long base = (long long)bb * 1050625;
  for (int i = t; i < 32800; i += 512) {
    int r = i / 1025, cc = i - r * 1025;
    float val = Cb[(long long)r0g * 1025 + i] + su[r0g + r] + sv[cc] - NORM;
    if (f) ((float*)outv)[base + (long long)r0g * 1025 + i] = val;
    else ((bf16*)outv)[base + (long long)r0g * 1025 + i] = __float2bfloat16(val);
  }
  if (blk == 0) {
    const float un = su[1024];
    for (int cc = t; cc < 1025; cc += 512) {
      float val = alpha + un + sv[cc] - NORM;
      if (f) ((float*)outv)[base + (long long)1024 * 1025 + cc] = val;
      else ((bf16*)outv)[base + (long long)1024 * 1025 + cc] = __float2bfloat16(val);
    }
  }
}

// ================================================================== launch
extern "C" void kernel_launch(void* const* d_in, const int* in_sizes, int n_in,
                              void* d_out, int out_size, void* d_ws, size_t ws_size,
                              hipStream_t stream) {
  const void* scores = d_in[0];
  const void* distance = d_in[1];
  const void* enc_W0 = d_in[2];
  const void* enc_b0 = d_in[3];
  const void* enc_bn = d_in[4];
  const void* enc_W1 = d_in[5];
  const void* enc_b1 = d_in[6];
  const void* gnn_Wqkv = d_in[7];
  const void* gnn_bqkv = d_in[8];
  const void* gnn_Wm = d_in[9];
  const void* gnn_bm = d_in[10];
  const void* gnn_W1 = d_in[11];
  const void* gnn_b1 = d_in[12];
  const void* gnn_bn = d_in[13];
  const void* gnn_W2 = d_in[14];
  const void* gnn_b2 = d_in[15];
  const void* final_W = d_in[16];
  const void* final_b = d_in[17];
  const void* alpha = d_in[18];
  (void)in_sizes; (void)n_in; (void)out_size; (void)ws_size;

  char* ws = (char*)d_ws;
  size_t off = 0;
  auto alloc = [&](size_t bytes) -> void* {
    void* p = ws + off;
    off += (bytes + 255) & ~(size_t)255;
    return p;
  };
  typedef unsigned short ush;
  int* flag = (int*)alloc(256);
  int* nvA = (int*)alloc(256);
  int* idxO = (int*)alloc(4096 * 4);
  float* valsO = (float*)alloc(4096 * 4);
  float* maskO = (float*)alloc(4096 * 4);
  ush* WH = (ush*)alloc((size_t)2818048 * 2);
  ush* WL = (ush*)alloc((size_t)2818048 * 2);
  ush* embH = (ush*)alloc((size_t)1048576 * 2);
  ush* embL = (ush*)alloc((size_t)1048576 * 2);
  ush* T0H = (ush*)alloc((size_t)1048576 * 2);
  ush* T0L = (ush*)alloc((size_t)1048576 * 2);
  ush* XH = (ush*)alloc((size_t)1048576 * 2);
  ush* XL = (ush*)alloc((size_t)1048576 * 2);
  float* Xf = (float*)alloc((size_t)1048576 * 4);
  float* QKVf = (float*)alloc((size_t)3145728 * 4);
  float* meanV = (float*)alloc(1024 * 4);
  ush* msgH = (ush*)alloc((size_t)1048576 * 2);
  ush* msgL = (ush*)alloc((size_t)1048576 * 2);
  ush* M2H = (ush*)alloc((size_t)1048576 * 2);
  ush* M2L = (ush*)alloc((size_t)1048576 * 2);
  ush* Y1H = (ush*)alloc((size_t)2097152 * 2);
  ush* Y1L = (ush*)alloc((size_t)2097152 * 2);
  ush* MDH = (ush*)alloc((size_t)1048576 * 2);
  ush* MDL = (ush*)alloc((size_t)1048576 * 2);
  float* Cpl = (float*)alloc((size_t)4 * 1050625 * 4);
  float* u = (float*)alloc(4100 * 4);
  float* v = (float*)alloc(4100 * 4);
  unsigned* flagsS = (unsigned*)alloc(256 * 4);

  hipMemsetAsync(u, 0, 4100 * 4, stream);
  hipMemsetAsync(v, 0, 4100 * 4, stream);
  hipMemsetAsync(flagsS, 0, 256 * 4, stream);

  static bool attrSet = false;
  if (!attrSet) {
    hipFuncSetAttribute(reinterpret_cast<const void*>(&k_sinkhorn),
                        hipFuncAttributeMaxDynamicSharedMemorySize, 139600);
    hipFuncSetAttribute(reinterpret_cast<const void*>(&k_front),
                        hipFuncAttributeMaxDynamicSharedMemorySize, 120000);
    attrSet = true;
  }

  const dim3 b256(256);
  k_front<<<4, 1024, 120000, stream>>>(scores, distance, flag, idxO, valsO,
                                       maskO, nvA);
  k_prep<<<11008, b256, 0, stream>>>(enc_W0, enc_W1, gnn_Wqkv, gnn_Wm, gnn_W1,
                                     gnn_W2, final_W, WH, WL, flag);
  k_emb<<<4096, b256, 0, stream>>>(idxO, valsO, distance, embH, embL, flag);

  // encoder
  gemm_pl<1, false, false><<<dim3(4, 64, 1), b256, 0, stream>>>(
      embH, embL, nullptr, nullptr, 256, WH + 0, WL + 0, enc_b0, enc_bn,
      nullptr, T0H, T0L, 256, 256, 256, 1.f, 0, 0, 0, 0, 0, 0, flag);
  gemm_pl<5, false, false><<<dim3(4, 64, 1), b256, 0, stream>>>(
      T0H, T0L, nullptr, nullptr, 256, WH + 65536, WL + 65536, enc_b1, nullptr,
      Xf, XH, XL, 256, 256, 256, 1.f, 0, 0, 0, 0, 0, 0, flag);

  for (int l = 0; l < 4; l++) {
    gemm_pl<3, false, false><<<dim3(12, 64, 1), b256, 0, stream>>>(
        XH, XL, nullptr, nullptr, 256, WH + 131072, WL + 131072, gnn_bqkv,
        nullptr, QKVf, nullptr, nullptr, 768, 768, 256, 1.f, 0, 0, 0,
        (long long)l * 196608, (long long)l * 768, 0, flag);
    k_meanv<<<16, b256, 0, stream>>>(QKVf, meanV);
    k_attn<<<dim3(16, 4, 4), b256, 0, stream>>>(QKVf, maskO, nvA, meanV, msgH,
                                                msgL);
    gemm_pl<0, false, false><<<dim3(4, 64, 1), b256, 0, stream>>>(
        msgH, msgL, nullptr, nullptr, 256, WH + 917504, WL + 917504, gnn_bm,
        nullptr, nullptr, M2H, M2L, 256, 256, 256, 1.f, 0, 0, 0,
        (long long)l * 65536, (long long)l * 256, 0, flag);
    gemm_pl<1, true, false><<<dim3(8, 64, 1), b256, 0, stream>>>(
        XH, XL, M2H, M2L, 256, WH + 1179648, WL + 1179648, gnn_b1, gnn_bn,
        nullptr, Y1H, Y1L, 512, 512, 512, 1.f, 0, 0, 0,
        (long long)l * 262144, (long long)l * 512, (long long)l * 2048, flag);
    gemm_pl<2, false, false><<<dim3(4, 64, 1), b256, 0, stream>>>(
        Y1H, Y1L, nullptr, nullptr, 512, WH + 2228224, WL + 2228224, gnn_b2,
        nullptr, Xf, XH, XL, 256, 256, 512, 1.f, 0, 0, 0,
        (long long)l * 131072, (long long)l * 256, 0, flag);
  }
  gemm_pl<0, false, false><<<dim3(4, 64, 1), b256, 0, stream>>>(
      XH, XL, nullptr, nullptr, 256, WH + 2752512, WL + 2752512, final_b,
      nullptr, nullptr, MDH, MDL, 256, 256, 256, 1.f, 0, 0, 0, 0, 0, 0, flag);
  gemm_pl<4, false, true><<<dim3(16, 16, 4), b256, 0, stream>>>(
      MDH, MDL, nullptr, nullptr, 256, MDH, MDL, nullptr, nullptr, Cpl, nullptr,
      nullptr, 1025, 1024, 256, 0.0625f, 262144, 262144, 1050625, 0, 0, 0, flag);
  k_border<<<16, b256, 0, stream>>>(Cpl, alpha, flag);
  k_sinkhorn<<<128, 512, 139600, stream>>>(Cpl, alpha, u, v, flagsS, d_out, flag);
}